// Round 5
// baseline (531.051 us; speedup 1.0000x reference)
//
#include <hip/hip_runtime.h>
#include <math.h>

#define NNODES 100000
#define NEDGES 3200000
#define ETOT   (NEDGES + NNODES)
#define IN_DIM 128
#define NH1    8
#define NC1    8
#define HC     64
#define OUTC   2
#define NEGSL  0.2f
#define L2E    1.44269504f

// ---------------- CSR build ----------------

__global__ void zero_ints(int* p, int n) {
    int i = blockIdx.x * blockDim.x + threadIdx.x;
    if (i < n) p[i] = 0;
}

// histogram + per-edge rank; 4 edges per thread for memory-level parallelism
__global__ void hist_rank(const int* __restrict__ ei, int* __restrict__ cnt,
                          int* __restrict__ rank) {
    int t = blockIdx.x * blockDim.x + threadIdx.x;   // NEDGES/4 threads exactly
    int i0 = t * 4;
    int4 d4 = *(const int4*)&ei[NEDGES + i0];
    int r0 = atomicAdd(&cnt[d4.x], 1);
    int r1 = atomicAdd(&cnt[d4.y], 1);
    int r2 = atomicAdd(&cnt[d4.z], 1);
    int r3 = atomicAdd(&cnt[d4.w], 1);
    *(int4*)&rank[i0] = make_int4(r0, r1, r2, r3);
}

// exclusive scan of (cnt[i] + 1) -> rowoff (block-local), block totals -> bsums
__global__ __launch_bounds__(256) void scan1(const int* cnt, int* rowoff, int* bsums) {
    int gid = blockIdx.x * 256 + threadIdx.x;
    int v = (gid < NNODES) ? (cnt[gid] + 1) : 0;   // +1 self-loop per node
    int lane = threadIdx.x & 63, w = threadIdx.x >> 6;
    int x = v;
    for (int off = 1; off < 64; off <<= 1) {
        int y = __shfl_up(x, off, 64);
        if (lane >= off) x += y;
    }
    __shared__ int wtot[4];
    if (lane == 63) wtot[w] = x;
    __syncthreads();
    int add = 0;
    for (int i = 0; i < w; i++) add += wtot[i];
    int incl = x + add;
    if (gid < NNODES) rowoff[gid] = incl - v;      // exclusive within block
    if (threadIdx.x == 255) bsums[blockIdx.x] = incl;
}

__global__ __launch_bounds__(512) void scan2(int* bsums, int nb) {
    int tid = threadIdx.x;
    int v = (tid < nb) ? bsums[tid] : 0;
    int lane = tid & 63, w = tid >> 6;
    int x = v;
    for (int off = 1; off < 64; off <<= 1) {
        int y = __shfl_up(x, off, 64);
        if (lane >= off) x += y;
    }
    __shared__ int wt[8];
    if (lane == 63) wt[w] = x;
    __syncthreads();
    int add = 0;
    for (int i = 0; i < w; i++) add += wt[i];
    if (tid < nb) bsums[tid] = x + add - v;        // exclusive
}

__global__ void scan3(int* rowoff, const int* bsums) {
    int gid = blockIdx.x * blockDim.x + threadIdx.x;
    if (gid < NNODES) rowoff[gid] = rowoff[gid] + bsums[gid >> 8];
    if (gid == 0) rowoff[NNODES] = ETOT;
}

// atomic-free scatter, 4 edges per thread
__global__ void scatter2(const int* __restrict__ ei, const int* __restrict__ rank,
                         const int* __restrict__ rowoff, int* __restrict__ srcs) {
    int t = blockIdx.x * blockDim.x + threadIdx.x;   // NEDGES/4 threads exactly
    int i0 = t * 4;
    int4 s4 = *(const int4*)&ei[i0];
    int4 d4 = *(const int4*)&ei[NEDGES + i0];
    int4 r4 = *(const int4*)&rank[i0];
    int o0 = rowoff[d4.x], o1 = rowoff[d4.y], o2 = rowoff[d4.z], o3 = rowoff[d4.w];
    srcs[o0 + r4.x] = s4.x;
    srcs[o1 + r4.y] = s4.y;
    srcs[o2 + r4.z] = s4.z;
    srcs[o3 + r4.w] = s4.w;
}

__global__ void scatter_self(const int* __restrict__ rowoff, int* __restrict__ srcs) {
    int n = blockIdx.x * blockDim.x + threadIdx.x;
    if (n < NNODES) srcs[rowoff[n + 1] - 1] = n;   // self-loop in last slot of row
}

// ---------------- layer 1 linear + attention logits ----------------

__global__ __launch_bounds__(256) void gemm1(const float* __restrict__ x,
                                             const float* __restrict__ W1,
                                             const float* __restrict__ a1s,
                                             const float* __restrict__ a1d,
                                             float* __restrict__ h1,
                                             float* __restrict__ al1s,
                                             float* __restrict__ al1d) {
    __shared__ float sW[IN_DIM * HC];   // 32 KB
    int tid = threadIdx.x;
    const float4* W4 = (const float4*)W1;
    float4* sW4 = (float4*)sW;
#pragma unroll
    for (int i = 0; i < 8; i++)          // 2048 float4 / 256 threads
        sW4[tid + i * 256] = W4[tid + i * 256];
    __syncthreads();

    int w = __builtin_amdgcn_readfirstlane(tid >> 6);
    int lane = tid & 63;
    int node0 = blockIdx.x * 16 + w * 4;       // 6250 blocks * 16 = 100000 exact
    const float* xr = x + (size_t)node0 * IN_DIM;

    float acc0 = 0.f, acc1 = 0.f, acc2 = 0.f, acc3 = 0.f;
#pragma unroll 8
    for (int k = 0; k < IN_DIM; k++) {
        float wv = sW[k * HC + lane];
        acc0 = fmaf(xr[k], wv, acc0);
        acc1 = fmaf(xr[IN_DIM + k], wv, acc1);
        acc2 = fmaf(xr[2 * IN_DIM + k], wv, acc2);
        acc3 = fmaf(xr[3 * IN_DIM + k], wv, acc3);
    }

    float accs[4] = {acc0, acc1, acc2, acc3};
    int head = lane >> 3, c = lane & 7;
    float as = a1s[head * NC1 + c], adv = a1d[head * NC1 + c];
#pragma unroll
    for (int n = 0; n < 4; n++) {
        int node = node0 + n;
        h1[(size_t)node * HC + lane] = accs[n];
        float ps = accs[n] * as;
        float pd = accs[n] * adv;
        for (int off = 1; off < 8; off <<= 1) {
            ps += __shfl_xor(ps, off, 64);
            pd += __shfl_xor(pd, off, 64);
        }
        if (c == 0) {
            al1s[node * NH1 + head] = ps;
            al1d[node * NH1 + head] = pd;
        }
    }
}

// ---------------- layer 1 aggregation ----------------
// wave per node; lane = head*8 + edge_slot. Each lane computes p for a
// DISTINCT (edge, head) pair (1 exp per pair — minimal). Accumulation
// redistributes p via ds_swizzle (8-lane-group broadcast, DS pipe) and
// reads h1 rows through readlane->SGPR base (scalar-pipe addressing).

__global__ __launch_bounds__(256) void agg1(const float* __restrict__ h1,
                                            const float* __restrict__ al1s,
                                            const float* __restrict__ al1d,
                                            const float* __restrict__ b1,
                                            const float* __restrict__ W2,
                                            const float* __restrict__ a2s,
                                            const float* __restrict__ a2d,
                                            const int* __restrict__ rowoff,
                                            const int* __restrict__ srcs,
                                            float* __restrict__ h2,
                                            float* __restrict__ al2s,
                                            float* __restrict__ al2d) {
    int w = threadIdx.x >> 6, lane = threadIdx.x & 63;
    int node = blockIdx.x * 4 + w;
    if (node >= NNODES) return;
    int h = lane >> 3, es = lane & 7;
    float ald = al1d[node * NH1 + h];
    int beg = rowoff[node], end = rowoff[node + 1];

    // phase 1: per-head max of al1s over sources (8 edges x 8 heads / iter)
    float mx = -1e30f;
    for (int base = beg; base < end; base += 8) {
        int idx = base + es;
        int s = srcs[idx < end ? idx : end - 1];
        float v = al1s[(s << 3) + h];
        if (idx < end) mx = fmaxf(mx, v);
    }
    mx = fmaxf(mx, __shfl_xor(mx, 1, 64));
    mx = fmaxf(mx, __shfl_xor(mx, 2, 64));
    mx = fmaxf(mx, __shfl_xor(mx, 4, 64));
    float xm = mx + ald;
    float maxe = fmaxf(xm, NEGSL * xm);    // LeakyReLU monotonic
    float mL2E = maxe * L2E;

    // phase 2: p per (edge,head) on its own lane; swizzle-broadcast to heads
    float den = 0.f, acc = 0.f;
    for (int base = beg; base < end; base += 8) {
        int idx = base + es;
        bool valid = idx < end;
        int s = srcs[valid ? idx : end - 1];
        float als = al1s[(s << 3) + h];
        float xx = als + ald;
        float lr = fmaxf(xx, NEGSL * xx);
        float p = exp2f(fmaf(lr, L2E, -mL2E));
        p = valid ? p : 0.f;
        den += p;
        int pbits = __float_as_int(p);
#define EDGE(J, IMM)                                                          \
        if (base + J < end) {                                                 \
            int sj = __builtin_amdgcn_readlane(s, J);                         \
            float pj = __int_as_float(__builtin_amdgcn_ds_swizzle(pbits, IMM)); \
            acc = fmaf(pj, h1[(size_t)sj * HC + lane], acc);                  \
        }
        EDGE(0, 0x0018) EDGE(1, 0x0038) EDGE(2, 0x0058) EDGE(3, 0x0078)
        EDGE(4, 0x0098) EDGE(5, 0x00B8) EDGE(6, 0x00D8) EDGE(7, 0x00F8)
#undef EDGE
    }
    // den: sum across edge-slot bits (0..2); result is per-head, matching lane's h
    den += __shfl_xor(den, 1, 64);
    den += __shfl_xor(den, 2, 64);
    den += __shfl_xor(den, 4, 64);

    float o = acc / den + b1[lane];
    o = (o > 0.f) ? o : expm1f(o);          // ELU
    // layer-2 linear: h2[node][oc] = sum_lane o * W2[lane][oc]
    float p0 = o * W2[lane * OUTC + 0];
    float p1 = o * W2[lane * OUTC + 1];
    for (int off = 1; off < 64; off <<= 1) {
        p0 += __shfl_xor(p0, off, 64);
        p1 += __shfl_xor(p1, off, 64);
    }
    if (lane == 0) {
        h2[node * 2 + 0] = p0;
        h2[node * 2 + 1] = p1;
        al2s[node] = p0 * a2s[0] + p1 * a2s[1];
        al2d[node] = p0 * a2d[0] + p1 * a2d[1];
    }
}

// ---------------- layer 2 aggregation (wave per node, lane per edge) ----------------

__global__ __launch_bounds__(256) void agg2(const float* __restrict__ h2,
                                            const float* __restrict__ al2s,
                                            const float* __restrict__ al2d,
                                            const float* __restrict__ b2,
                                            const int* __restrict__ rowoff,
                                            const int* __restrict__ srcs,
                                            float* __restrict__ out) {
    int w = threadIdx.x >> 6, lane = threadIdx.x & 63;
    int n = blockIdx.x * 4 + w;
    if (n >= NNODES) return;
    float ald = al2d[n];
    int beg = rowoff[n], end = rowoff[n + 1];
    float m = -1e30f, den = 0.f, a0 = 0.f, a1 = 0.f;
    for (int base = beg; base < end; base += 64) {
        int idx = base + lane;
        bool valid = idx < end;
        int s = valid ? srcs[idx] : 0;
        float e = -1e30f, q0 = 0.f, q1 = 0.f;
        if (valid) {
            float xx = al2s[s] + ald;
            e = fmaxf(xx, NEGSL * xx);
            q0 = h2[s * 2 + 0];
            q1 = h2[s * 2 + 1];
        }
        float cm = e;
        for (int off = 1; off < 64; off <<= 1) cm = fmaxf(cm, __shfl_xor(cm, off, 64));
        float nm = fmaxf(m, cm);
        float sc = __expf(m - nm);
        float p = valid ? __expf(e - nm) : 0.f;
        float pd = p, pa0 = p * q0, pa1 = p * q1;
        for (int off = 1; off < 64; off <<= 1) {
            pd  += __shfl_xor(pd, off, 64);
            pa0 += __shfl_xor(pa0, off, 64);
            pa1 += __shfl_xor(pa1, off, 64);
        }
        den = den * sc + pd;
        a0  = a0 * sc + pa0;
        a1  = a1 * sc + pa1;
        m = nm;
    }
    if (lane == 0) {
        out[n * 2 + 0] = a0 / den + b2[0];
        out[n * 2 + 1] = a1 / den + b2[1];
    }
}

// ---------------- launch ----------------

extern "C" void kernel_launch(void* const* d_in, const int* in_sizes, int n_in,
                              void* d_out, int out_size, void* d_ws, size_t ws_size,
                              hipStream_t stream) {
    const float* x   = (const float*)d_in[0];
    const int*   ei  = (const int*)  d_in[1];
    // d_in[2] = edge_attr (unused by reference)
    const float* W1  = (const float*)d_in[3];
    const float* a1s = (const float*)d_in[4];
    const float* a1d = (const float*)d_in[5];
    const float* b1  = (const float*)d_in[6];
    const float* W2  = (const float*)d_in[7];
    const float* a2s = (const float*)d_in[8];
    const float* a2d = (const float*)d_in[9];
    const float* b2  = (const float*)d_in[10];
    float* out = (float*)d_out;

    // workspace layout. NOTE: rank aliases h1 — rank is only live during the
    // CSR build; h1 is first written by gemm1, which launches after scatter2.
    float* fws   = (float*)d_ws;
    float* h1    = fws;                                 // N*64 floats (25.6MB)
    int*   rank  = (int*)fws;                           // E ints (12.8MB) — aliases h1
    float* al1s_ = h1 + (size_t)NNODES * HC;            // N*8
    float* al1d_ = al1s_ + (size_t)NNODES * NH1;        // N*8
    float* h2    = al1d_ + (size_t)NNODES * NH1;        // N*2
    float* al2s_ = h2 + (size_t)NNODES * 2;             // N
    float* al2d_ = al2s_ + NNODES;                      // N
    int* rowoff  = (int*)(al2d_ + NNODES);              // N+1
    int* cnt     = rowoff + NNODES + 1;                 // N
    int* srcs    = cnt + NNODES;                        // E+N
    int* bsums   = srcs + ETOT;                         // ~391

    const int NB_N   = (NNODES + 255) / 256;   // 391
    const int NB_E4  = NEDGES / 4 / 256;       // 3125 (exact)
    const int NB_N4  = (NNODES + 3) / 4;       // 25000
    const int NB_G   = NNODES / 16;            // 6250 (exact)

    // CSR build
    zero_ints<<<NB_N, 256, 0, stream>>>(cnt, NNODES);
    hist_rank<<<NB_E4, 256, 0, stream>>>(ei, cnt, rank);
    scan1<<<NB_N, 256, 0, stream>>>(cnt, rowoff, bsums);
    scan2<<<1, 512, 0, stream>>>(bsums, NB_N);
    scan3<<<NB_N, 256, 0, stream>>>(rowoff, bsums);
    scatter2<<<NB_E4, 256, 0, stream>>>(ei, rank, rowoff, srcs);
    scatter_self<<<NB_N, 256, 0, stream>>>(rowoff, srcs);

    // layer 1 linear + logits
    gemm1<<<NB_G, 256, 0, stream>>>(x, W1, a1s, a1d, h1, al1s_, al1d_);

    // layer 1 aggregation + finalize + layer-2 linear/logits
    agg1<<<NB_N4, 256, 0, stream>>>(h1, al1s_, al1d_, b1, W2, a2s, a2d,
                                    rowoff, srcs, h2, al2s_, al2d_);

    // layer 2 aggregation -> output
    agg2<<<NB_N4, 256, 0, stream>>>(h2, al2s_, al2d_, b2, rowoff, srcs, out);
}

// Round 6
// 457.921 us; speedup vs baseline: 1.1597x; 1.1597x over previous
//
#include <hip/hip_runtime.h>
#include <math.h>

#define NNODES 100000
#define NEDGES 3200000
#define ETOT   (NEDGES + NNODES)
#define IN_DIM 128
#define NH1    8
#define NC1    8
#define HC     64
#define OUTC   2
#define NEGSL  0.2f
#define L2E    1.44269504f

// ---------------- CSR build ----------------

__global__ void zero_ints(int* p, int n) {
    int i = blockIdx.x * blockDim.x + threadIdx.x;
    if (i < n) p[i] = 0;
}

// histogram + per-edge rank; 8 edges per thread for memory-level parallelism
__global__ void hist_rank(const int* __restrict__ ei, int* __restrict__ cnt,
                          int* __restrict__ rank) {
    int t = blockIdx.x * blockDim.x + threadIdx.x;
    int i0 = t * 8;
    if (i0 >= NEDGES) return;
    int4 dA = *(const int4*)&ei[NEDGES + i0];
    int4 dB = *(const int4*)&ei[NEDGES + i0 + 4];
    int r0 = atomicAdd(&cnt[dA.x], 1);
    int r1 = atomicAdd(&cnt[dA.y], 1);
    int r2 = atomicAdd(&cnt[dA.z], 1);
    int r3 = atomicAdd(&cnt[dA.w], 1);
    int r4 = atomicAdd(&cnt[dB.x], 1);
    int r5 = atomicAdd(&cnt[dB.y], 1);
    int r6 = atomicAdd(&cnt[dB.z], 1);
    int r7 = atomicAdd(&cnt[dB.w], 1);
    *(int4*)&rank[i0]     = make_int4(r0, r1, r2, r3);
    *(int4*)&rank[i0 + 4] = make_int4(r4, r5, r6, r7);
}

// exclusive scan of (cnt[i] + 1) -> rowoff (block-local), block totals -> bsums
__global__ __launch_bounds__(256) void scan1(const int* cnt, int* rowoff, int* bsums) {
    int gid = blockIdx.x * 256 + threadIdx.x;
    int v = (gid < NNODES) ? (cnt[gid] + 1) : 0;   // +1 self-loop per node
    int lane = threadIdx.x & 63, w = threadIdx.x >> 6;
    int x = v;
    for (int off = 1; off < 64; off <<= 1) {
        int y = __shfl_up(x, off, 64);
        if (lane >= off) x += y;
    }
    __shared__ int wtot[4];
    if (lane == 63) wtot[w] = x;
    __syncthreads();
    int add = 0;
    for (int i = 0; i < w; i++) add += wtot[i];
    int incl = x + add;
    if (gid < NNODES) rowoff[gid] = incl - v;      // exclusive within block
    if (threadIdx.x == 255) bsums[blockIdx.x] = incl;
}

__global__ __launch_bounds__(512) void scan2(int* bsums, int nb) {
    int tid = threadIdx.x;
    int v = (tid < nb) ? bsums[tid] : 0;
    int lane = tid & 63, w = tid >> 6;
    int x = v;
    for (int off = 1; off < 64; off <<= 1) {
        int y = __shfl_up(x, off, 64);
        if (lane >= off) x += y;
    }
    __shared__ int wt[8];
    if (lane == 63) wt[w] = x;
    __syncthreads();
    int add = 0;
    for (int i = 0; i < w; i++) add += wt[i];
    if (tid < nb) bsums[tid] = x + add - v;        // exclusive
}

__global__ void scan3(int* rowoff, const int* bsums) {
    int gid = blockIdx.x * blockDim.x + threadIdx.x;
    if (gid < NNODES) rowoff[gid] = rowoff[gid] + bsums[gid >> 8];
    if (gid == 0) rowoff[NNODES] = ETOT;
}

// atomic-free scatter, 8 edges per thread
__global__ void scatter2(const int* __restrict__ ei, const int* __restrict__ rank,
                         const int* __restrict__ rowoff, int* __restrict__ srcs) {
    int t = blockIdx.x * blockDim.x + threadIdx.x;
    int i0 = t * 8;
    if (i0 >= NEDGES) return;
    int4 sA = *(const int4*)&ei[i0];
    int4 sB = *(const int4*)&ei[i0 + 4];
    int4 dA = *(const int4*)&ei[NEDGES + i0];
    int4 dB = *(const int4*)&ei[NEDGES + i0 + 4];
    int4 rA = *(const int4*)&rank[i0];
    int4 rB = *(const int4*)&rank[i0 + 4];
    srcs[rowoff[dA.x] + rA.x] = sA.x;
    srcs[rowoff[dA.y] + rA.y] = sA.y;
    srcs[rowoff[dA.z] + rA.z] = sA.z;
    srcs[rowoff[dA.w] + rA.w] = sA.w;
    srcs[rowoff[dB.x] + rB.x] = sB.x;
    srcs[rowoff[dB.y] + rB.y] = sB.y;
    srcs[rowoff[dB.z] + rB.z] = sB.z;
    srcs[rowoff[dB.w] + rB.w] = sB.w;
}

__global__ void scatter_self(const int* __restrict__ rowoff, int* __restrict__ srcs) {
    int n = blockIdx.x * blockDim.x + threadIdx.x;
    if (n < NNODES) srcs[rowoff[n + 1] - 1] = n;   // self-loop in last slot of row
}

// ---------------- layer 1 linear + attention logit exponentials ----------------
// alE[node*8+h] = (exp(al_src), exp(0.2*al_src)); al1d kept raw.

__global__ __launch_bounds__(256) void gemm1(const float* __restrict__ x,
                                             const float* __restrict__ W1,
                                             const float* __restrict__ a1s,
                                             const float* __restrict__ a1d,
                                             float* __restrict__ h1,
                                             float2* __restrict__ alE,
                                             float* __restrict__ al1d) {
    __shared__ float sW[IN_DIM * HC];   // 32 KB
    int tid = threadIdx.x;
    const float4* W4 = (const float4*)W1;
    float4* sW4 = (float4*)sW;
#pragma unroll
    for (int i = 0; i < 8; i++)          // 2048 float4 / 256 threads
        sW4[tid + i * 256] = W4[tid + i * 256];
    __syncthreads();

    int w = __builtin_amdgcn_readfirstlane(tid >> 6);
    int lane = tid & 63;
    int node0 = blockIdx.x * 16 + w * 4;       // 6250 blocks * 16 = 100000 exact
    const float* xr = x + (size_t)node0 * IN_DIM;

    float acc0 = 0.f, acc1 = 0.f, acc2 = 0.f, acc3 = 0.f;
#pragma unroll 8
    for (int k = 0; k < IN_DIM; k++) {
        float wv = sW[k * HC + lane];
        acc0 = fmaf(xr[k], wv, acc0);
        acc1 = fmaf(xr[IN_DIM + k], wv, acc1);
        acc2 = fmaf(xr[2 * IN_DIM + k], wv, acc2);
        acc3 = fmaf(xr[3 * IN_DIM + k], wv, acc3);
    }

    float accs[4] = {acc0, acc1, acc2, acc3};
    int head = lane >> 3, c = lane & 7;
    float as = a1s[head * NC1 + c], adv = a1d[head * NC1 + c];
#pragma unroll
    for (int n = 0; n < 4; n++) {
        int node = node0 + n;
        h1[node * HC + lane] = accs[n];
        float ps = accs[n] * as;
        float pd = accs[n] * adv;
        for (int off = 1; off < 8; off <<= 1) {
            ps += __shfl_xor(ps, off, 64);
            pd += __shfl_xor(pd, off, 64);
        }
        if (c == 0) {
            alE[node * NH1 + head] = make_float2(exp2f(ps * L2E),
                                                 exp2f(ps * (NEGSL * L2E)));
            al1d[node * NH1 + head] = pd;
        }
    }
}

// ---------------- layer 1 aggregation ----------------
// wave per node. exp(LeakyReLU(als+ald)) == max(E1s*E1d, E2s*E2d) — no max
// pass, no exp in the loop, the softmax shift cancels in acc/den.
// Epilogue: /den, +b1, ELU, layer-2 linear + logit exponentials (fused).

__global__ __launch_bounds__(256) void agg1(const float* __restrict__ h1,
                                            const float2* __restrict__ alE,
                                            const float* __restrict__ al1d,
                                            const float* __restrict__ b1,
                                            const float* __restrict__ W2,
                                            const float* __restrict__ a2s,
                                            const float* __restrict__ a2d,
                                            const int* __restrict__ rowoff,
                                            const int* __restrict__ srcs,
                                            float* __restrict__ h2,
                                            float2* __restrict__ al2E,
                                            float* __restrict__ al2d) {
    int w = threadIdx.x >> 6, lane = threadIdx.x & 63;
    int node = blockIdx.x * 4 + w;
    if (node >= NNODES) return;
    int h = lane >> 3;
    float ald = al1d[node * NH1 + h];
    float E1d = exp2f(ald * L2E);
    float E2d = exp2f(ald * (NEGSL * L2E));
    int beg = rowoff[node], end = rowoff[node + 1];

    float den = 0.f, acc = 0.f, denB = 0.f, accB = 0.f;
    int i = beg;
    for (; i + 4 <= end; i += 4) {
        int s0 = srcs[i], s1 = srcs[i + 1], s2 = srcs[i + 2], s3 = srcs[i + 3];
        float2 e0 = alE[s0 * NH1 + h];
        float2 e1 = alE[s1 * NH1 + h];
        float2 e2 = alE[s2 * NH1 + h];
        float2 e3 = alE[s3 * NH1 + h];
        float hv0 = h1[s0 * HC + lane];
        float hv1 = h1[s1 * HC + lane];
        float hv2 = h1[s2 * HC + lane];
        float hv3 = h1[s3 * HC + lane];
        float p0 = fmaxf(e0.x * E1d, e0.y * E2d);
        float p1 = fmaxf(e1.x * E1d, e1.y * E2d);
        float p2 = fmaxf(e2.x * E1d, e2.y * E2d);
        float p3 = fmaxf(e3.x * E1d, e3.y * E2d);
        den  += p0;  acc  = fmaf(p0, hv0, acc);
        denB += p1;  accB = fmaf(p1, hv1, accB);
        den  += p2;  acc  = fmaf(p2, hv2, acc);
        denB += p3;  accB = fmaf(p3, hv3, accB);
    }
    for (; i < end; ++i) {
        int s0 = srcs[i];
        float2 e0 = alE[s0 * NH1 + h];
        float hv0 = h1[s0 * HC + lane];
        float p0 = fmaxf(e0.x * E1d, e0.y * E2d);
        den += p0; acc = fmaf(p0, hv0, acc);
    }
    den += denB; acc += accB;

    float o = acc / den + b1[lane];
    o = (o > 0.f) ? o : expm1f(o);          // ELU
    // layer-2 linear: h2[node][oc] = sum_lane o * W2[lane][oc]
    float p0 = o * W2[lane * OUTC + 0];
    float p1 = o * W2[lane * OUTC + 1];
    for (int off = 1; off < 64; off <<= 1) {
        p0 += __shfl_xor(p0, off, 64);
        p1 += __shfl_xor(p1, off, 64);
    }
    if (lane == 0) {
        h2[node * 2 + 0] = p0;
        h2[node * 2 + 1] = p1;
        float l2s = p0 * a2s[0] + p1 * a2s[1];
        float l2d = p0 * a2d[0] + p1 * a2d[1];
        al2E[node] = make_float2(exp2f(l2s * L2E), exp2f(l2s * (NEGSL * L2E)));
        al2d[node] = l2d;
    }
}

// ---------------- layer 2 aggregation (wave per node, lane per edge) ----------------

__global__ __launch_bounds__(256) void agg2(const float* __restrict__ h2,
                                            const float2* __restrict__ al2E,
                                            const float* __restrict__ al2d,
                                            const float* __restrict__ b2,
                                            const int* __restrict__ rowoff,
                                            const int* __restrict__ srcs,
                                            float* __restrict__ out) {
    int w = threadIdx.x >> 6, lane = threadIdx.x & 63;
    int n = blockIdx.x * 4 + w;
    if (n >= NNODES) return;
    float ald = al2d[n];
    float E1d = exp2f(ald * L2E);
    float E2d = exp2f(ald * (NEGSL * L2E));
    int beg = rowoff[n], end = rowoff[n + 1];
    float den = 0.f, a0 = 0.f, a1 = 0.f;
    for (int idx = beg + lane; idx < end; idx += 64) {
        int s = srcs[idx];
        float2 es = al2E[s];
        float2 q = *(const float2*)&h2[s * 2];
        float p = fmaxf(es.x * E1d, es.y * E2d);
        den += p;
        a0 = fmaf(p, q.x, a0);
        a1 = fmaf(p, q.y, a1);
    }
    for (int off = 1; off < 64; off <<= 1) {
        den += __shfl_xor(den, off, 64);
        a0  += __shfl_xor(a0, off, 64);
        a1  += __shfl_xor(a1, off, 64);
    }
    if (lane == 0) {
        out[n * 2 + 0] = a0 / den + b2[0];
        out[n * 2 + 1] = a1 / den + b2[1];
    }
}

// ---------------- launch ----------------

extern "C" void kernel_launch(void* const* d_in, const int* in_sizes, int n_in,
                              void* d_out, int out_size, void* d_ws, size_t ws_size,
                              hipStream_t stream) {
    const float* x   = (const float*)d_in[0];
    const int*   ei  = (const int*)  d_in[1];
    // d_in[2] = edge_attr (unused by reference)
    const float* W1  = (const float*)d_in[3];
    const float* a1s = (const float*)d_in[4];
    const float* a1d = (const float*)d_in[5];
    const float* b1  = (const float*)d_in[6];
    const float* W2  = (const float*)d_in[7];
    const float* a2s = (const float*)d_in[8];
    const float* a2d = (const float*)d_in[9];
    const float* b2  = (const float*)d_in[10];
    float* out = (float*)d_out;

    // workspace layout. NOTE: rank aliases h1 — rank is only live during the
    // CSR build; h1 is first written by gemm1, which launches after scatter2.
    float* fws    = (float*)d_ws;
    float* h1     = fws;                                 // N*64 floats (25.6MB)
    int*   rank   = (int*)fws;                           // E ints (12.8MB) — aliases h1
    float2* alE   = (float2*)(h1 + (size_t)NNODES * HC); // N*8 float2 (6.4MB)
    float* al1d_  = (float*)(alE + (size_t)NNODES * NH1);// N*8
    float* h2     = al1d_ + (size_t)NNODES * NH1;        // N*2
    float2* al2E  = (float2*)(h2 + (size_t)NNODES * 2);  // N float2
    float* al2d_  = (float*)(al2E + NNODES);             // N
    int* rowoff   = (int*)(al2d_ + NNODES);              // N+1
    int* cnt      = rowoff + NNODES + 1;                 // N
    int* srcs     = cnt + NNODES;                        // E+N
    int* bsums    = srcs + ETOT;                         // ~391

    const int NB_N   = (NNODES + 255) / 256;          // 391
    const int NB_E8  = (NEDGES / 8 + 255) / 256;      // 1563
    const int NB_N4  = (NNODES + 3) / 4;              // 25000
    const int NB_G   = NNODES / 16;                   // 6250 (exact)

    // CSR build
    zero_ints<<<NB_N, 256, 0, stream>>>(cnt, NNODES);
    hist_rank<<<NB_E8, 256, 0, stream>>>(ei, cnt, rank);
    scan1<<<NB_N, 256, 0, stream>>>(cnt, rowoff, bsums);
    scan2<<<1, 512, 0, stream>>>(bsums, NB_N);
    scan3<<<NB_N, 256, 0, stream>>>(rowoff, bsums);
    scatter2<<<NB_E8, 256, 0, stream>>>(ei, rank, rowoff, srcs);
    scatter_self<<<NB_N, 256, 0, stream>>>(rowoff, srcs);

    // layer 1 linear + logit exponentials
    gemm1<<<NB_G, 256, 0, stream>>>(x, W1, a1s, a1d, h1, alE, al1d_);

    // layer 1 aggregation + finalize + layer-2 linear/logits
    agg1<<<NB_N4, 256, 0, stream>>>(h1, alE, al1d_, b1, W2, a2s, a2d,
                                    rowoff, srcs, h2, al2E, al2d_);

    // layer 2 aggregation -> output
    agg2<<<NB_N4, 256, 0, stream>>>(h2, al2E, al2d_, b2, rowoff, srcs, out);
}

// Round 7
// 445.602 us; speedup vs baseline: 1.1918x; 1.0276x over previous
//
#include <hip/hip_runtime.h>
#include <math.h>

#define NNODES 100000
#define NEDGES 3200000
#define ETOT   (NEDGES + NNODES)
#define IN_DIM 128
#define NH1    8
#define NC1    8
#define HC     64
#define OUTC   2
#define NEGSL  0.2f
#define L2E    1.44269504f

// ---------------- CSR build ----------------

__global__ void zero_ints(int* p, int n) {
    int i = blockIdx.x * blockDim.x + threadIdx.x;
    if (i < n) p[i] = 0;
}

// histogram + per-edge rank; 8 edges per thread for memory-level parallelism
__global__ void hist_rank(const int* __restrict__ ei, int* __restrict__ cnt,
                          int* __restrict__ rank) {
    int t = blockIdx.x * blockDim.x + threadIdx.x;
    int i0 = t * 8;
    if (i0 >= NEDGES) return;
    int4 dA = *(const int4*)&ei[NEDGES + i0];
    int4 dB = *(const int4*)&ei[NEDGES + i0 + 4];
    int r0 = atomicAdd(&cnt[dA.x], 1);
    int r1 = atomicAdd(&cnt[dA.y], 1);
    int r2 = atomicAdd(&cnt[dA.z], 1);
    int r3 = atomicAdd(&cnt[dA.w], 1);
    int r4 = atomicAdd(&cnt[dB.x], 1);
    int r5 = atomicAdd(&cnt[dB.y], 1);
    int r6 = atomicAdd(&cnt[dB.z], 1);
    int r7 = atomicAdd(&cnt[dB.w], 1);
    *(int4*)&rank[i0]     = make_int4(r0, r1, r2, r3);
    *(int4*)&rank[i0 + 4] = make_int4(r4, r5, r6, r7);
}

// exclusive scan of (cnt[i] + 1) -> rowoff (block-local), block totals -> bsums
__global__ __launch_bounds__(256) void scan1(const int* cnt, int* rowoff, int* bsums) {
    int gid = blockIdx.x * 256 + threadIdx.x;
    int v = (gid < NNODES) ? (cnt[gid] + 1) : 0;   // +1 self-loop per node
    int lane = threadIdx.x & 63, w = threadIdx.x >> 6;
    int x = v;
    for (int off = 1; off < 64; off <<= 1) {
        int y = __shfl_up(x, off, 64);
        if (lane >= off) x += y;
    }
    __shared__ int wtot[4];
    if (lane == 63) wtot[w] = x;
    __syncthreads();
    int add = 0;
    for (int i = 0; i < w; i++) add += wtot[i];
    int incl = x + add;
    if (gid < NNODES) rowoff[gid] = incl - v;      // exclusive within block
    if (threadIdx.x == 255) bsums[blockIdx.x] = incl;
}

__global__ __launch_bounds__(512) void scan2(int* bsums, int nb) {
    int tid = threadIdx.x;
    int v = (tid < nb) ? bsums[tid] : 0;
    int lane = tid & 63, w = tid >> 6;
    int x = v;
    for (int off = 1; off < 64; off <<= 1) {
        int y = __shfl_up(x, off, 64);
        if (lane >= off) x += y;
    }
    __shared__ int wt[8];
    if (lane == 63) wt[w] = x;
    __syncthreads();
    int add = 0;
    for (int i = 0; i < w; i++) add += wt[i];
    if (tid < nb) bsums[tid] = x + add - v;        // exclusive
}

// finalize rowoff AND write the self-loop source (last slot of each row)
__global__ void scan3(int* __restrict__ rowoff, const int* __restrict__ bsums,
                      const int* __restrict__ cnt, int* __restrict__ srcs) {
    int gid = blockIdx.x * blockDim.x + threadIdx.x;
    if (gid < NNODES) {
        int r = rowoff[gid] + bsums[gid >> 8];
        rowoff[gid] = r;
        srcs[r + cnt[gid]] = gid;      // self-loop slot
    }
    if (gid == 0) rowoff[NNODES] = ETOT;
}

// atomic-free scatter, 8 edges per thread
__global__ void scatter2(const int* __restrict__ ei, const int* __restrict__ rank,
                         const int* __restrict__ rowoff, int* __restrict__ srcs) {
    int t = blockIdx.x * blockDim.x + threadIdx.x;
    int i0 = t * 8;
    if (i0 >= NEDGES) return;
    int4 sA = *(const int4*)&ei[i0];
    int4 sB = *(const int4*)&ei[i0 + 4];
    int4 dA = *(const int4*)&ei[NEDGES + i0];
    int4 dB = *(const int4*)&ei[NEDGES + i0 + 4];
    int4 rA = *(const int4*)&rank[i0];
    int4 rB = *(const int4*)&rank[i0 + 4];
    srcs[rowoff[dA.x] + rA.x] = sA.x;
    srcs[rowoff[dA.y] + rA.y] = sA.y;
    srcs[rowoff[dA.z] + rA.z] = sA.z;
    srcs[rowoff[dA.w] + rA.w] = sA.w;
    srcs[rowoff[dB.x] + rB.x] = sB.x;
    srcs[rowoff[dB.y] + rB.y] = sB.y;
    srcs[rowoff[dB.z] + rB.z] = sB.z;
    srcs[rowoff[dB.w] + rB.w] = sB.w;
}

// ---------------- layer 1 linear + attention logit exponentials ----------------
// alE[node*8+h] = (exp(al_src), exp(0.2*al_src)); al1d kept raw.

__global__ __launch_bounds__(256) void gemm1(const float* __restrict__ x,
                                             const float* __restrict__ W1,
                                             const float* __restrict__ a1s,
                                             const float* __restrict__ a1d,
                                             float* __restrict__ h1,
                                             float2* __restrict__ alE,
                                             float* __restrict__ al1d) {
    __shared__ float sW[IN_DIM * HC];   // 32 KB
    int tid = threadIdx.x;
    const float4* W4 = (const float4*)W1;
    float4* sW4 = (float4*)sW;
#pragma unroll
    for (int i = 0; i < 8; i++)          // 2048 float4 / 256 threads
        sW4[tid + i * 256] = W4[tid + i * 256];
    __syncthreads();

    int w = __builtin_amdgcn_readfirstlane(tid >> 6);
    int lane = tid & 63;
    int node0 = blockIdx.x * 16 + w * 4;       // 6250 blocks * 16 = 100000 exact
    const float* xr = x + (size_t)node0 * IN_DIM;

    float acc0 = 0.f, acc1 = 0.f, acc2 = 0.f, acc3 = 0.f;
#pragma unroll 8
    for (int k = 0; k < IN_DIM; k++) {
        float wv = sW[k * HC + lane];
        acc0 = fmaf(xr[k], wv, acc0);
        acc1 = fmaf(xr[IN_DIM + k], wv, acc1);
        acc2 = fmaf(xr[2 * IN_DIM + k], wv, acc2);
        acc3 = fmaf(xr[3 * IN_DIM + k], wv, acc3);
    }

    float accs[4] = {acc0, acc1, acc2, acc3};
    int head = lane >> 3, c = lane & 7;
    float as = a1s[head * NC1 + c], adv = a1d[head * NC1 + c];
#pragma unroll
    for (int n = 0; n < 4; n++) {
        int node = node0 + n;
        h1[node * HC + lane] = accs[n];
        float ps = accs[n] * as;
        float pd = accs[n] * adv;
        for (int off = 1; off < 8; off <<= 1) {
            ps += __shfl_xor(ps, off, 64);
            pd += __shfl_xor(pd, off, 64);
        }
        if (c == 0) {
            alE[node * NH1 + head] = make_float2(exp2f(ps * L2E),
                                                 exp2f(ps * (NEGSL * L2E)));
            al1d[node * NH1 + head] = pd;
        }
    }
}

// ---------------- layer 1 aggregation ----------------
// wave per node. exp(LeakyReLU(als+ald)) == max(E1s*E1d, E2s*E2d); softmax
// shift cancels in acc/den. srcs index & loop bounds are wave-uniform —
// readfirstlane them so srcs[i] scalarizes (s_load) and h1/alE loads become
// SGPR-base + small-voffset coalesced loads (no per-lane 64-bit addr chains).

__global__ __launch_bounds__(256) void agg1(const float* __restrict__ h1,
                                            const float2* __restrict__ alE,
                                            const float* __restrict__ al1d,
                                            const float* __restrict__ b1,
                                            const float* __restrict__ W2,
                                            const float* __restrict__ a2s,
                                            const float* __restrict__ a2d,
                                            const int* __restrict__ rowoff,
                                            const int* __restrict__ srcs,
                                            float* __restrict__ h2,
                                            float2* __restrict__ al2E,
                                            float* __restrict__ al2d) {
    int w = threadIdx.x >> 6, lane = threadIdx.x & 63;
    int node = blockIdx.x * 4 + w;
    if (node >= NNODES) return;
    int h = lane >> 3;
    float ald = al1d[node * NH1 + h];
    float E1d = exp2f(ald * L2E);
    float E2d = exp2f(ald * (NEGSL * L2E));
    int beg = __builtin_amdgcn_readfirstlane(rowoff[node]);
    int end = __builtin_amdgcn_readfirstlane(rowoff[node + 1]);

    float den = 0.f, acc = 0.f, denB = 0.f, accB = 0.f;
    int i = beg;
    for (; i + 4 <= end; i += 4) {
        int s0 = __builtin_amdgcn_readfirstlane(srcs[i]);
        int s1 = __builtin_amdgcn_readfirstlane(srcs[i + 1]);
        int s2 = __builtin_amdgcn_readfirstlane(srcs[i + 2]);
        int s3 = __builtin_amdgcn_readfirstlane(srcs[i + 3]);
        float2 e0 = alE[s0 * NH1 + h];
        float2 e1 = alE[s1 * NH1 + h];
        float2 e2 = alE[s2 * NH1 + h];
        float2 e3 = alE[s3 * NH1 + h];
        float hv0 = h1[s0 * HC + lane];
        float hv1 = h1[s1 * HC + lane];
        float hv2 = h1[s2 * HC + lane];
        float hv3 = h1[s3 * HC + lane];
        float p0 = fmaxf(e0.x * E1d, e0.y * E2d);
        float p1 = fmaxf(e1.x * E1d, e1.y * E2d);
        float p2 = fmaxf(e2.x * E1d, e2.y * E2d);
        float p3 = fmaxf(e3.x * E1d, e3.y * E2d);
        den  += p0;  acc  = fmaf(p0, hv0, acc);
        denB += p1;  accB = fmaf(p1, hv1, accB);
        den  += p2;  acc  = fmaf(p2, hv2, acc);
        denB += p3;  accB = fmaf(p3, hv3, accB);
    }
    for (; i < end; ++i) {
        int s0 = __builtin_amdgcn_readfirstlane(srcs[i]);
        float2 e0 = alE[s0 * NH1 + h];
        float hv0 = h1[s0 * HC + lane];
        float p0 = fmaxf(e0.x * E1d, e0.y * E2d);
        den += p0; acc = fmaf(p0, hv0, acc);
    }
    den += denB; acc += accB;

    float o = acc / den + b1[lane];
    o = (o > 0.f) ? o : expm1f(o);          // ELU
    // layer-2 linear: h2[node][oc] = sum_lane o * W2[lane][oc]
    float p0 = o * W2[lane * OUTC + 0];
    float p1 = o * W2[lane * OUTC + 1];
    for (int off = 1; off < 64; off <<= 1) {
        p0 += __shfl_xor(p0, off, 64);
        p1 += __shfl_xor(p1, off, 64);
    }
    if (lane == 0) {
        h2[node * 2 + 0] = p0;
        h2[node * 2 + 1] = p1;
        float l2s = p0 * a2s[0] + p1 * a2s[1];
        float l2d = p0 * a2d[0] + p1 * a2d[1];
        al2E[node] = make_float2(exp2f(l2s * L2E), exp2f(l2s * (NEGSL * L2E)));
        al2d[node] = l2d;
    }
}

// ---------------- layer 2 aggregation (wave per node, lane per edge) ----------------

__global__ __launch_bounds__(256) void agg2(const float* __restrict__ h2,
                                            const float2* __restrict__ al2E,
                                            const float* __restrict__ al2d,
                                            const float* __restrict__ b2,
                                            const int* __restrict__ rowoff,
                                            const int* __restrict__ srcs,
                                            float* __restrict__ out) {
    int w = threadIdx.x >> 6, lane = threadIdx.x & 63;
    int n = blockIdx.x * 4 + w;
    if (n >= NNODES) return;
    float ald = al2d[n];
    float E1d = exp2f(ald * L2E);
    float E2d = exp2f(ald * (NEGSL * L2E));
    int beg = rowoff[n], end = rowoff[n + 1];
    float den = 0.f, a0 = 0.f, a1 = 0.f;
    for (int idx = beg + lane; idx < end; idx += 64) {
        int s = srcs[idx];
        float2 es = al2E[s];
        float2 q = *(const float2*)&h2[s * 2];
        float p = fmaxf(es.x * E1d, es.y * E2d);
        den += p;
        a0 = fmaf(p, q.x, a0);
        a1 = fmaf(p, q.y, a1);
    }
    for (int off = 1; off < 64; off <<= 1) {
        den += __shfl_xor(den, off, 64);
        a0  += __shfl_xor(a0, off, 64);
        a1  += __shfl_xor(a1, off, 64);
    }
    if (lane == 0) {
        out[n * 2 + 0] = a0 / den + b2[0];
        out[n * 2 + 1] = a1 / den + b2[1];
    }
}

// ---------------- launch ----------------

extern "C" void kernel_launch(void* const* d_in, const int* in_sizes, int n_in,
                              void* d_out, int out_size, void* d_ws, size_t ws_size,
                              hipStream_t stream) {
    const float* x   = (const float*)d_in[0];
    const int*   ei  = (const int*)  d_in[1];
    // d_in[2] = edge_attr (unused by reference)
    const float* W1  = (const float*)d_in[3];
    const float* a1s = (const float*)d_in[4];
    const float* a1d = (const float*)d_in[5];
    const float* b1  = (const float*)d_in[6];
    const float* W2  = (const float*)d_in[7];
    const float* a2s = (const float*)d_in[8];
    const float* a2d = (const float*)d_in[9];
    const float* b2  = (const float*)d_in[10];
    float* out = (float*)d_out;

    // workspace layout. NOTE: rank aliases h1 — rank is only live during the
    // CSR build; h1 is first written by gemm1, which launches after scatter2.
    float* fws    = (float*)d_ws;
    float* h1     = fws;                                 // N*64 floats (25.6MB)
    int*   rank   = (int*)fws;                           // E ints (12.8MB) — aliases h1
    float2* alE   = (float2*)(h1 + (size_t)NNODES * HC); // N*8 float2 (6.4MB)
    float* al1d_  = (float*)(alE + (size_t)NNODES * NH1);// N*8
    float* h2     = al1d_ + (size_t)NNODES * NH1;        // N*2
    float2* al2E  = (float2*)(h2 + (size_t)NNODES * 2);  // N float2
    float* al2d_  = (float*)(al2E + NNODES);             // N
    int* rowoff   = (int*)(al2d_ + NNODES);              // N+1
    int* cnt      = rowoff + NNODES + 1;                 // N
    int* srcs     = cnt + NNODES;                        // E+N
    int* bsums    = srcs + ETOT;                         // ~391

    const int NB_N   = (NNODES + 255) / 256;          // 391
    const int NB_E8  = (NEDGES / 8 + 255) / 256;      // 1563
    const int NB_N4  = (NNODES + 3) / 4;              // 25000
    const int NB_G   = NNODES / 16;                   // 6250 (exact)

    // CSR build
    zero_ints<<<NB_N, 256, 0, stream>>>(cnt, NNODES);
    hist_rank<<<NB_E8, 256, 0, stream>>>(ei, cnt, rank);
    scan1<<<NB_N, 256, 0, stream>>>(cnt, rowoff, bsums);
    scan2<<<1, 512, 0, stream>>>(bsums, NB_N);
    scan3<<<NB_N, 256, 0, stream>>>(rowoff, bsums, cnt, srcs);  // + self-loops
    scatter2<<<NB_E8, 256, 0, stream>>>(ei, rank, rowoff, srcs);

    // layer 1 linear + logit exponentials
    gemm1<<<NB_G, 256, 0, stream>>>(x, W1, a1s, a1d, h1, alE, al1d_);

    // layer 1 aggregation + finalize + layer-2 linear/logits
    agg1<<<NB_N4, 256, 0, stream>>>(h1, alE, al1d_, b1, W2, a2s, a2d,
                                    rowoff, srcs, h2, al2E, al2d_);

    // layer 2 aggregation -> output
    agg2<<<NB_N4, 256, 0, stream>>>(h2, al2E, al2d_, b2, rowoff, srcs, out);
}

// Round 8
// 301.596 us; speedup vs baseline: 1.7608x; 1.4775x over previous
//
#include <hip/hip_runtime.h>
#include <math.h>

#define NNODES 100000
#define NEDGES 3200000
#define ETOT   (NEDGES + NNODES)
#define IN_DIM 128
#define NH1    8
#define NC1    8
#define HC     64
#define OUTC   2
#define NEGSL  0.2f
#define L2E    1.44269504f

// counting-sort CSR build parameters
#define NBUCK 391                 // ceil(NNODES/256) coarse buckets (dst>>8)
#define EPB   8192                // edges per block in hist/scatter
#define NBLK  391                 // ceil(NEDGES/EPB)
#define TOTC  (NBUCK * NBLK)      // 152881 (bucket-major counts array)

// ---------------- CSR build (two-level LDS counting sort) ----------------

// per-block LDS histogram over coarse buckets -> counts[bucket][block]
__global__ __launch_bounds__(256) void histA(const int* __restrict__ ei,
                                             int* __restrict__ carr) {
    __shared__ int lh[NBUCK];
    int tid = threadIdx.x;
    for (int i = tid; i < NBUCK; i += 256) lh[i] = 0;
    __syncthreads();
    const int* dptr = ei + NEDGES;
    int base = blockIdx.x * EPB;
#pragma unroll
    for (int i = 0; i < EPB / 1024; i++) {
        int idx = base + i * 1024 + tid * 4;
        if (idx < NEDGES) {
            int4 d4 = *(const int4*)&dptr[idx];
            atomicAdd(&lh[d4.x >> 8], 1);
            atomicAdd(&lh[d4.y >> 8], 1);
            atomicAdd(&lh[d4.z >> 8], 1);
            atomicAdd(&lh[d4.w >> 8], 1);
        }
    }
    __syncthreads();
    for (int i = tid; i < NBUCK; i += 256)
        carr[i * NBLK + blockIdx.x] = lh[i];
}

// exclusive scan over TOTC counts (block-local) + block sums
__global__ __launch_bounds__(256) void scanA(int* __restrict__ carr,
                                             int* __restrict__ bsums) {
    int gid = blockIdx.x * 256 + threadIdx.x;
    int v = (gid < TOTC) ? carr[gid] : 0;
    int lane = threadIdx.x & 63, w = threadIdx.x >> 6;
    int x = v;
    for (int off = 1; off < 64; off <<= 1) {
        int y = __shfl_up(x, off, 64);
        if (lane >= off) x += y;
    }
    __shared__ int wt[4];
    if (lane == 63) wt[w] = x;
    __syncthreads();
    int add = 0;
    for (int i = 0; i < w; i++) add += wt[i];
    int incl = x + add;
    if (gid < TOTC) carr[gid] = incl - v;
    if (threadIdx.x == 255) bsums[blockIdx.x] = incl;
}

// scan of block sums (nb <= 1024)
__global__ __launch_bounds__(1024) void scanB(int* __restrict__ bsums, int nb) {
    int tid = threadIdx.x;
    int v = (tid < nb) ? bsums[tid] : 0;
    int lane = tid & 63, w = tid >> 6;
    int x = v;
    for (int off = 1; off < 64; off <<= 1) {
        int y = __shfl_up(x, off, 64);
        if (lane >= off) x += y;
    }
    __shared__ int wt[16];
    if (lane == 63) wt[w] = x;
    __syncthreads();
    int add = 0;
    for (int i = 0; i < w; i++) add += wt[i];
    if (tid < nb) bsums[tid] = x + add - v;        // exclusive
}

__global__ __launch_bounds__(256) void scanC(int* __restrict__ carr,
                                             const int* __restrict__ bsums) {
    int gid = blockIdx.x * 256 + threadIdx.x;
    if (gid < TOTC) carr[gid] += bsums[gid >> 8];
}

// scatter edges into bucket-contiguous regions; rank via LDS atomic (any
// order within (block,bucket) is valid). Pack src (17b) | dst_low8 (<<17).
__global__ __launch_bounds__(256) void scatC(const int* __restrict__ ei,
                                             const int* __restrict__ soff,
                                             int* __restrict__ ebuf) {
    __shared__ int soffL[NBUCK];
    __shared__ int lh[NBUCK];
    int tid = threadIdx.x;
    for (int i = tid; i < NBUCK; i += 256) {
        soffL[i] = soff[i * NBLK + blockIdx.x];
        lh[i] = 0;
    }
    __syncthreads();
    int base = blockIdx.x * EPB;
#pragma unroll
    for (int i = 0; i < EPB / 1024; i++) {
        int idx = base + i * 1024 + tid * 4;
        if (idx < NEDGES) {
            int4 s4 = *(const int4*)&ei[idx];
            int4 d4 = *(const int4*)&ei[NEDGES + idx];
            int b0 = d4.x >> 8, b1 = d4.y >> 8, b2 = d4.z >> 8, b3 = d4.w >> 8;
            int r0 = atomicAdd(&lh[b0], 1);
            int r1 = atomicAdd(&lh[b1], 1);
            int r2 = atomicAdd(&lh[b2], 1);
            int r3 = atomicAdd(&lh[b3], 1);
            ebuf[soffL[b0] + r0] = s4.x | ((d4.x & 255) << 17);
            ebuf[soffL[b1] + r1] = s4.y | ((d4.y & 255) << 17);
            ebuf[soffL[b2] + r2] = s4.z | ((d4.z & 255) << 17);
            ebuf[soffL[b3] + r3] = s4.w | ((d4.w & 255) << 17);
        }
    }
}

// one block per bucket: fine count (256 nodes), LDS scan (+1 self-loop per
// node), emit rowoff + self-loops + final srcs.
__global__ __launch_bounds__(256) void buildD(const int* __restrict__ soff,
                                              const int* __restrict__ ebuf,
                                              int* __restrict__ rowoff,
                                              int* __restrict__ srcs) {
    int b = blockIdx.x, tid = threadIdx.x;
    int nb = min(256, NNODES - b * 256);
    int ebeg = soff[b * NBLK];
    int eend = (b == NBUCK - 1) ? NEDGES : soff[(b + 1) * NBLK];
    __shared__ int cnt2[256];
    __shared__ int rowL[256];
    __shared__ int wsum[4];
    cnt2[tid] = 0;
    __syncthreads();
    for (int e = ebeg + tid; e < eend; e += 256)
        atomicAdd(&cnt2[(ebuf[e] >> 17) & 255], 1);
    __syncthreads();
    // exclusive scan of (cnt2 + 1)
    int v = (tid < nb) ? cnt2[tid] + 1 : 0;
    int lane = tid & 63, w = tid >> 6;
    int x = v;
    for (int off = 1; off < 64; off <<= 1) {
        int y = __shfl_up(x, off, 64);
        if (lane >= off) x += y;
    }
    if (lane == 63) wsum[w] = x;
    __syncthreads();
    int add = 0;
    for (int i = 0; i < w; i++) add += wsum[i];
    int fbase = ebeg + b * 256;              // + self-loops of earlier buckets
    int row = fbase + x + add - v;           // exclusive
    if (tid < nb) {
        rowL[tid] = row;
        int gnode = b * 256 + tid;
        rowoff[gnode] = row;
        srcs[row + cnt2[tid]] = gnode;       // self-loop in last slot of row
        if (gnode == NNODES - 1) rowoff[NNODES] = ETOT;
    }
    __syncthreads();
    cnt2[tid] = 0;                           // reuse as rank counters
    __syncthreads();
    for (int e = ebeg + tid; e < eend; e += 256) {
        int wv = ebuf[e];
        int dl = (wv >> 17) & 255;
        int r = atomicAdd(&cnt2[dl], 1);
        srcs[rowL[dl] + r] = wv & 0x1FFFF;
    }
}

// ---------------- layer 1 linear + attention logit exponentials ----------------
// alE[node*8+h] = (exp(al_src), exp(0.2*al_src)); al1d kept raw.

__global__ __launch_bounds__(256) void gemm1(const float* __restrict__ x,
                                             const float* __restrict__ W1,
                                             const float* __restrict__ a1s,
                                             const float* __restrict__ a1d,
                                             float* __restrict__ h1,
                                             float2* __restrict__ alE,
                                             float* __restrict__ al1d) {
    __shared__ float sW[IN_DIM * HC];   // 32 KB
    int tid = threadIdx.x;
    const float4* W4 = (const float4*)W1;
    float4* sW4 = (float4*)sW;
#pragma unroll
    for (int i = 0; i < 8; i++)          // 2048 float4 / 256 threads
        sW4[tid + i * 256] = W4[tid + i * 256];
    __syncthreads();

    int w = __builtin_amdgcn_readfirstlane(tid >> 6);
    int lane = tid & 63;
    int node0 = blockIdx.x * 16 + w * 4;       // 6250 blocks * 16 = 100000 exact
    const float* xr = x + (size_t)node0 * IN_DIM;

    float acc0 = 0.f, acc1 = 0.f, acc2 = 0.f, acc3 = 0.f;
#pragma unroll 8
    for (int k = 0; k < IN_DIM; k++) {
        float wv = sW[k * HC + lane];
        acc0 = fmaf(xr[k], wv, acc0);
        acc1 = fmaf(xr[IN_DIM + k], wv, acc1);
        acc2 = fmaf(xr[2 * IN_DIM + k], wv, acc2);
        acc3 = fmaf(xr[3 * IN_DIM + k], wv, acc3);
    }

    float accs[4] = {acc0, acc1, acc2, acc3};
    int head = lane >> 3, c = lane & 7;
    float as = a1s[head * NC1 + c], adv = a1d[head * NC1 + c];
#pragma unroll
    for (int n = 0; n < 4; n++) {
        int node = node0 + n;
        h1[node * HC + lane] = accs[n];
        float ps = accs[n] * as;
        float pd = accs[n] * adv;
        for (int off = 1; off < 8; off <<= 1) {
            ps += __shfl_xor(ps, off, 64);
            pd += __shfl_xor(pd, off, 64);
        }
        if (c == 0) {
            alE[node * NH1 + head] = make_float2(exp2f(ps * L2E),
                                                 exp2f(ps * (NEGSL * L2E)));
            al1d[node * NH1 + head] = pd;
        }
    }
}

// ---------------- layer 1 aggregation ----------------
// wave per node. exp(LeakyReLU(als+ald)) == max(E1s*E1d, E2s*E2d); softmax
// shift cancels in acc/den. srcs index & loop bounds are wave-uniform —
// readfirstlane them so srcs[i] scalarizes and h1/alE loads become
// SGPR-base + small-voffset coalesced loads.

__global__ __launch_bounds__(256) void agg1(const float* __restrict__ h1,
                                            const float2* __restrict__ alE,
                                            const float* __restrict__ al1d,
                                            const float* __restrict__ b1,
                                            const float* __restrict__ W2,
                                            const float* __restrict__ a2s,
                                            const float* __restrict__ a2d,
                                            const int* __restrict__ rowoff,
                                            const int* __restrict__ srcs,
                                            float* __restrict__ h2,
                                            float2* __restrict__ al2E,
                                            float* __restrict__ al2d) {
    int w = threadIdx.x >> 6, lane = threadIdx.x & 63;
    int node = blockIdx.x * 4 + w;
    if (node >= NNODES) return;
    int h = lane >> 3;
    float ald = al1d[node * NH1 + h];
    float E1d = exp2f(ald * L2E);
    float E2d = exp2f(ald * (NEGSL * L2E));
    int beg = __builtin_amdgcn_readfirstlane(rowoff[node]);
    int end = __builtin_amdgcn_readfirstlane(rowoff[node + 1]);

    float den = 0.f, acc = 0.f, denB = 0.f, accB = 0.f;
    int i = beg;
    for (; i + 4 <= end; i += 4) {
        int s0 = __builtin_amdgcn_readfirstlane(srcs[i]);
        int s1 = __builtin_amdgcn_readfirstlane(srcs[i + 1]);
        int s2 = __builtin_amdgcn_readfirstlane(srcs[i + 2]);
        int s3 = __builtin_amdgcn_readfirstlane(srcs[i + 3]);
        float2 e0 = alE[s0 * NH1 + h];
        float2 e1 = alE[s1 * NH1 + h];
        float2 e2 = alE[s2 * NH1 + h];
        float2 e3 = alE[s3 * NH1 + h];
        float hv0 = h1[s0 * HC + lane];
        float hv1 = h1[s1 * HC + lane];
        float hv2 = h1[s2 * HC + lane];
        float hv3 = h1[s3 * HC + lane];
        float p0 = fmaxf(e0.x * E1d, e0.y * E2d);
        float p1 = fmaxf(e1.x * E1d, e1.y * E2d);
        float p2 = fmaxf(e2.x * E1d, e2.y * E2d);
        float p3 = fmaxf(e3.x * E1d, e3.y * E2d);
        den  += p0;  acc  = fmaf(p0, hv0, acc);
        denB += p1;  accB = fmaf(p1, hv1, accB);
        den  += p2;  acc  = fmaf(p2, hv2, acc);
        denB += p3;  accB = fmaf(p3, hv3, accB);
    }
    for (; i < end; ++i) {
        int s0 = __builtin_amdgcn_readfirstlane(srcs[i]);
        float2 e0 = alE[s0 * NH1 + h];
        float hv0 = h1[s0 * HC + lane];
        float p0 = fmaxf(e0.x * E1d, e0.y * E2d);
        den += p0; acc = fmaf(p0, hv0, acc);
    }
    den += denB; acc += accB;

    float o = acc / den + b1[lane];
    o = (o > 0.f) ? o : expm1f(o);          // ELU
    // layer-2 linear: h2[node][oc] = sum_lane o * W2[lane][oc]
    float p0 = o * W2[lane * OUTC + 0];
    float p1 = o * W2[lane * OUTC + 1];
    for (int off = 1; off < 64; off <<= 1) {
        p0 += __shfl_xor(p0, off, 64);
        p1 += __shfl_xor(p1, off, 64);
    }
    if (lane == 0) {
        h2[node * 2 + 0] = p0;
        h2[node * 2 + 1] = p1;
        float l2s = p0 * a2s[0] + p1 * a2s[1];
        float l2d = p0 * a2d[0] + p1 * a2d[1];
        al2E[node] = make_float2(exp2f(l2s * L2E), exp2f(l2s * (NEGSL * L2E)));
        al2d[node] = l2d;
    }
}

// ---------------- layer 2 aggregation (wave per node, lane per edge) ----------------

__global__ __launch_bounds__(256) void agg2(const float* __restrict__ h2,
                                            const float2* __restrict__ al2E,
                                            const float* __restrict__ al2d,
                                            const float* __restrict__ b2,
                                            const int* __restrict__ rowoff,
                                            const int* __restrict__ srcs,
                                            float* __restrict__ out) {
    int w = threadIdx.x >> 6, lane = threadIdx.x & 63;
    int n = blockIdx.x * 4 + w;
    if (n >= NNODES) return;
    float ald = al2d[n];
    float E1d = exp2f(ald * L2E);
    float E2d = exp2f(ald * (NEGSL * L2E));
    int beg = rowoff[n], end = rowoff[n + 1];
    float den = 0.f, a0 = 0.f, a1 = 0.f;
    for (int idx = beg + lane; idx < end; idx += 64) {
        int s = srcs[idx];
        float2 es = al2E[s];
        float2 q = *(const float2*)&h2[s * 2];
        float p = fmaxf(es.x * E1d, es.y * E2d);
        den += p;
        a0 = fmaf(p, q.x, a0);
        a1 = fmaf(p, q.y, a1);
    }
    for (int off = 1; off < 64; off <<= 1) {
        den += __shfl_xor(den, off, 64);
        a0  += __shfl_xor(a0, off, 64);
        a1  += __shfl_xor(a1, off, 64);
    }
    if (lane == 0) {
        out[n * 2 + 0] = a0 / den + b2[0];
        out[n * 2 + 1] = a1 / den + b2[1];
    }
}

// ---------------- launch ----------------

extern "C" void kernel_launch(void* const* d_in, const int* in_sizes, int n_in,
                              void* d_out, int out_size, void* d_ws, size_t ws_size,
                              hipStream_t stream) {
    const float* x   = (const float*)d_in[0];
    const int*   ei  = (const int*)  d_in[1];
    // d_in[2] = edge_attr (unused by reference)
    const float* W1  = (const float*)d_in[3];
    const float* a1s = (const float*)d_in[4];
    const float* a1d = (const float*)d_in[5];
    const float* b1  = (const float*)d_in[6];
    const float* W2  = (const float*)d_in[7];
    const float* a2s = (const float*)d_in[8];
    const float* a2d = (const float*)d_in[9];
    const float* b2  = (const float*)d_in[10];
    float* out = (float*)d_out;

    // workspace layout. ebuf/carr/bsums alias h1 (dead before gemm1 runs).
    float* fws    = (float*)d_ws;
    float* h1     = fws;                                 // N*64 floats (25.6MB)
    int*   ebuf   = (int*)fws;                           // NEDGES ints — aliases h1
    int*   carr   = ebuf + NEDGES;                       // TOTC ints — aliases h1
    int*   bsums  = carr + TOTC;                         // ~598 ints — aliases h1
    float2* alE   = (float2*)(h1 + (size_t)NNODES * HC); // N*8 float2 (6.4MB)
    float* al1d_  = (float*)(alE + (size_t)NNODES * NH1);// N*8
    float* h2     = al1d_ + (size_t)NNODES * NH1;        // N*2
    float2* al2E  = (float2*)(h2 + (size_t)NNODES * 2);  // N float2
    float* al2d_  = (float*)(al2E + NNODES);             // N
    int* rowoff   = (int*)(al2d_ + NNODES);              // N+1
    int* srcs     = rowoff + NNODES + 1;                 // E+N

    const int NB_SC  = (TOTC + 255) / 256;            // 598
    const int NB_N4  = (NNODES + 3) / 4;              // 25000
    const int NB_G   = NNODES / 16;                   // 6250 (exact)

    // CSR build (LDS counting sort; no global atomics)
    histA<<<NBLK, 256, 0, stream>>>(ei, carr);
    scanA<<<NB_SC, 256, 0, stream>>>(carr, bsums);
    scanB<<<1, 1024, 0, stream>>>(bsums, NB_SC);
    scanC<<<NB_SC, 256, 0, stream>>>(carr, bsums);
    scatC<<<NBLK, 256, 0, stream>>>(ei, carr, ebuf);
    buildD<<<NBUCK, 256, 0, stream>>>(carr, ebuf, rowoff, srcs);

    // layer 1 linear + logit exponentials
    gemm1<<<NB_G, 256, 0, stream>>>(x, W1, a1s, a1d, h1, alE, al1d_);

    // layer 1 aggregation + finalize + layer-2 linear/logits
    agg1<<<NB_N4, 256, 0, stream>>>(h1, alE, al1d_, b1, W2, a2s, a2d,
                                    rowoff, srcs, h2, al2E, al2d_);

    // layer 2 aggregation -> output
    agg2<<<NB_N4, 256, 0, stream>>>(h2, al2E, al2d_, b2, rowoff, srcs, out);
}

// Round 9
// 282.246 us; speedup vs baseline: 1.8815x; 1.0686x over previous
//
#include <hip/hip_runtime.h>
#include <math.h>

#define NNODES 100000
#define NEDGES 3200000
#define ETOT   (NEDGES + NNODES)
#define IN_DIM 128
#define NH1    8
#define NC1    8
#define HC     64
#define OUTC   2
#define NEGSL  0.2f
#define L2E    1.44269504f

// counting-sort CSR build parameters
#define NBUCK 391                 // ceil(NNODES/256) coarse buckets (dst>>8)
#define EPB   2048                // edges per block in hist/scatter
#define NBLK  1563                // ceil(NEDGES/EPB)
#define TOTC  (NBUCK * NBLK)      // 611133 (bucket-major counts array)

// ---------------- CSR build (two-level LDS counting sort) ----------------

// per-block LDS histogram over coarse buckets -> counts[bucket][block]
__global__ __launch_bounds__(256) void histA(const int* __restrict__ ei,
                                             int* __restrict__ carr) {
    __shared__ int lh[NBUCK];
    int tid = threadIdx.x;
    for (int i = tid; i < NBUCK; i += 256) lh[i] = 0;
    __syncthreads();
    const int* dptr = ei + NEDGES;
    int base = blockIdx.x * EPB;
#pragma unroll
    for (int i = 0; i < EPB / 1024; i++) {
        int idx = base + i * 1024 + tid * 4;
        if (idx < NEDGES) {
            int4 d4 = *(const int4*)&dptr[idx];
            atomicAdd(&lh[d4.x >> 8], 1);
            atomicAdd(&lh[d4.y >> 8], 1);
            atomicAdd(&lh[d4.z >> 8], 1);
            atomicAdd(&lh[d4.w >> 8], 1);
        }
    }
    __syncthreads();
    for (int i = tid; i < NBUCK; i += 256)
        carr[i * NBLK + blockIdx.x] = lh[i];
}

// exclusive scan over TOTC counts (block-local) + block sums
__global__ __launch_bounds__(256) void scanA(int* __restrict__ carr,
                                             int* __restrict__ bsums) {
    int gid = blockIdx.x * 256 + threadIdx.x;
    int v = (gid < TOTC) ? carr[gid] : 0;
    int lane = threadIdx.x & 63, w = threadIdx.x >> 6;
    int x = v;
    for (int off = 1; off < 64; off <<= 1) {
        int y = __shfl_up(x, off, 64);
        if (lane >= off) x += y;
    }
    __shared__ int wt[4];
    if (lane == 63) wt[w] = x;
    __syncthreads();
    int add = 0;
    for (int i = 0; i < w; i++) add += wt[i];
    int incl = x + add;
    if (gid < TOTC) carr[gid] = incl - v;
    if (threadIdx.x == 255) bsums[blockIdx.x] = incl;
}

// scan of block sums; 4 elements per thread (supports nb <= 4096)
__global__ __launch_bounds__(1024) void scanB(int* __restrict__ bsums, int nb) {
    int tid = threadIdx.x;
    int base = tid * 4;
    int v[4]; int tot = 0;
#pragma unroll
    for (int j = 0; j < 4; j++) {
        v[j] = (base + j < nb) ? bsums[base + j] : 0;
        tot += v[j];
    }
    int lane = tid & 63, w = tid >> 6;
    int x = tot;
    for (int off = 1; off < 64; off <<= 1) {
        int y = __shfl_up(x, off, 64);
        if (lane >= off) x += y;
    }
    __shared__ int wt[16];
    if (lane == 63) wt[w] = x;
    __syncthreads();
    int add = 0;
    for (int i = 0; i < w; i++) add += wt[i];
    int pre = x + add - tot;   // exclusive prefix of this thread's chunk
#pragma unroll
    for (int j = 0; j < 4; j++) {
        if (base + j < nb) bsums[base + j] = pre;
        pre += v[j];
    }
}

__global__ __launch_bounds__(256) void scanC(int* __restrict__ carr,
                                             const int* __restrict__ bsums) {
    int gid = blockIdx.x * 256 + threadIdx.x;
    if (gid < TOTC) carr[gid] += bsums[gid >> 8];
}

// scatter edges into bucket-contiguous regions; rank via LDS atomic (any
// order within (block,bucket) is valid). Pack src (17b) | dst_low8 (<<17).
__global__ __launch_bounds__(256) void scatC(const int* __restrict__ ei,
                                             const int* __restrict__ soff,
                                             int* __restrict__ ebuf) {
    __shared__ int soffL[NBUCK];
    __shared__ int lh[NBUCK];
    int tid = threadIdx.x;
    for (int i = tid; i < NBUCK; i += 256) {
        soffL[i] = soff[i * NBLK + blockIdx.x];
        lh[i] = 0;
    }
    __syncthreads();
    int base = blockIdx.x * EPB;
#pragma unroll
    for (int i = 0; i < EPB / 1024; i++) {
        int idx = base + i * 1024 + tid * 4;
        if (idx < NEDGES) {
            int4 s4 = *(const int4*)&ei[idx];
            int4 d4 = *(const int4*)&ei[NEDGES + idx];
            int b0 = d4.x >> 8, b1 = d4.y >> 8, b2 = d4.z >> 8, b3 = d4.w >> 8;
            int r0 = atomicAdd(&lh[b0], 1);
            int r1 = atomicAdd(&lh[b1], 1);
            int r2 = atomicAdd(&lh[b2], 1);
            int r3 = atomicAdd(&lh[b3], 1);
            ebuf[soffL[b0] + r0] = s4.x | ((d4.x & 255) << 17);
            ebuf[soffL[b1] + r1] = s4.y | ((d4.y & 255) << 17);
            ebuf[soffL[b2] + r2] = s4.z | ((d4.z & 255) << 17);
            ebuf[soffL[b3] + r3] = s4.w | ((d4.w & 255) << 17);
        }
    }
}

// one block per bucket: fine count (256 nodes), LDS scan (+1 self-loop per
// node), emit rowoff + self-loops + final srcs.
__global__ __launch_bounds__(256) void buildD(const int* __restrict__ soff,
                                              const int* __restrict__ ebuf,
                                              int* __restrict__ rowoff,
                                              int* __restrict__ srcs) {
    int b = blockIdx.x, tid = threadIdx.x;
    int nb = min(256, NNODES - b * 256);
    int ebeg = soff[b * NBLK];
    int eend = (b == NBUCK - 1) ? NEDGES : soff[(b + 1) * NBLK];
    __shared__ int cnt2[256];
    __shared__ int rowL[256];
    __shared__ int wsum[4];
    cnt2[tid] = 0;
    __syncthreads();
    for (int e = ebeg + tid; e < eend; e += 256)
        atomicAdd(&cnt2[(ebuf[e] >> 17) & 255], 1);
    __syncthreads();
    // exclusive scan of (cnt2 + 1)
    int v = (tid < nb) ? cnt2[tid] + 1 : 0;
    int lane = tid & 63, w = tid >> 6;
    int x = v;
    for (int off = 1; off < 64; off <<= 1) {
        int y = __shfl_up(x, off, 64);
        if (lane >= off) x += y;
    }
    if (lane == 63) wsum[w] = x;
    __syncthreads();
    int add = 0;
    for (int i = 0; i < w; i++) add += wsum[i];
    int fbase = ebeg + b * 256;              // + self-loops of earlier buckets
    int row = fbase + x + add - v;           // exclusive
    if (tid < nb) {
        rowL[tid] = row;
        int gnode = b * 256 + tid;
        rowoff[gnode] = row;
        srcs[row + cnt2[tid]] = gnode;       // self-loop in last slot of row
        if (gnode == NNODES - 1) rowoff[NNODES] = ETOT;
    }
    __syncthreads();
    cnt2[tid] = 0;                           // reuse as rank counters
    __syncthreads();
    for (int e = ebeg + tid; e < eend; e += 256) {
        int wv = ebuf[e];
        int dl = (wv >> 17) & 255;
        int r = atomicAdd(&cnt2[dl], 1);
        srcs[rowL[dl] + r] = wv & 0x1FFFF;
    }
}

// ---------------- layer 1 linear + attention logit exponentials ----------------
// h1 stored as bf16 (RNE) — halves the agg1 gather traffic.
// alE[node*8+h] = (exp(al_src), exp(0.2*al_src)); al1d kept raw.

__global__ __launch_bounds__(256) void gemm1(const float* __restrict__ x,
                                             const float* __restrict__ W1,
                                             const float* __restrict__ a1s,
                                             const float* __restrict__ a1d,
                                             unsigned short* __restrict__ h1b,
                                             float2* __restrict__ alE,
                                             float* __restrict__ al1d) {
    __shared__ float sW[IN_DIM * HC];   // 32 KB
    int tid = threadIdx.x;
    const float4* W4 = (const float4*)W1;
    float4* sW4 = (float4*)sW;
#pragma unroll
    for (int i = 0; i < 8; i++)          // 2048 float4 / 256 threads
        sW4[tid + i * 256] = W4[tid + i * 256];
    __syncthreads();

    int w = __builtin_amdgcn_readfirstlane(tid >> 6);
    int lane = tid & 63;
    int node0 = blockIdx.x * 16 + w * 4;       // 6250 blocks * 16 = 100000 exact
    const float* xr = x + (size_t)node0 * IN_DIM;

    float acc0 = 0.f, acc1 = 0.f, acc2 = 0.f, acc3 = 0.f;
#pragma unroll 8
    for (int k = 0; k < IN_DIM; k++) {
        float wv = sW[k * HC + lane];
        acc0 = fmaf(xr[k], wv, acc0);
        acc1 = fmaf(xr[IN_DIM + k], wv, acc1);
        acc2 = fmaf(xr[2 * IN_DIM + k], wv, acc2);
        acc3 = fmaf(xr[3 * IN_DIM + k], wv, acc3);
    }

    float accs[4] = {acc0, acc1, acc2, acc3};
    int head = lane >> 3, c = lane & 7;
    float as = a1s[head * NC1 + c], adv = a1d[head * NC1 + c];
#pragma unroll
    for (int n = 0; n < 4; n++) {
        int node = node0 + n;
        unsigned int u = __float_as_uint(accs[n]);
        h1b[node * HC + lane] =
            (unsigned short)((u + 0x7FFF + ((u >> 16) & 1)) >> 16);  // RNE bf16
        float ps = accs[n] * as;
        float pd = accs[n] * adv;
        for (int off = 1; off < 8; off <<= 1) {
            ps += __shfl_xor(ps, off, 64);
            pd += __shfl_xor(pd, off, 64);
        }
        if (c == 0) {
            alE[node * NH1 + head] = make_float2(exp2f(ps * L2E),
                                                 exp2f(ps * (NEGSL * L2E)));
            al1d[node * NH1 + head] = pd;
        }
    }
}

// ---------------- layer 1 aggregation ----------------
// wave per node. exp(LeakyReLU(als+ald)) == max(E1s*E1d, E2s*E2d); softmax
// shift cancels in acc/den. srcs index & loop bounds are wave-uniform —
// readfirstlane them so srcs[i] scalarizes and h1/alE loads become
// SGPR-base + small-voffset coalesced loads. h1 is bf16 (128B/row gather).
// Epilogue fuses: /den, +b1, ELU, layer-2 linear, layer-2 logit exps,
// packed as nd2 = (E1, E2, h2_0, h2_1) for a single 16B gather in agg2.

__global__ __launch_bounds__(256) void agg1(const unsigned short* __restrict__ h1b,
                                            const float2* __restrict__ alE,
                                            const float* __restrict__ al1d,
                                            const float* __restrict__ b1,
                                            const float* __restrict__ W2,
                                            const float* __restrict__ a2s,
                                            const float* __restrict__ a2d,
                                            const int* __restrict__ rowoff,
                                            const int* __restrict__ srcs,
                                            float4* __restrict__ nd2,
                                            float* __restrict__ al2d) {
    int w = threadIdx.x >> 6, lane = threadIdx.x & 63;
    int node = blockIdx.x * 4 + w;
    if (node >= NNODES) return;
    int h = lane >> 3;
    float ald = al1d[node * NH1 + h];
    float E1d = exp2f(ald * L2E);
    float E2d = exp2f(ald * (NEGSL * L2E));
    int beg = __builtin_amdgcn_readfirstlane(rowoff[node]);
    int end = __builtin_amdgcn_readfirstlane(rowoff[node + 1]);

    float den = 0.f, acc = 0.f, denB = 0.f, accB = 0.f;
    int i = beg;
    for (; i + 4 <= end; i += 4) {
        int s0 = __builtin_amdgcn_readfirstlane(srcs[i]);
        int s1 = __builtin_amdgcn_readfirstlane(srcs[i + 1]);
        int s2 = __builtin_amdgcn_readfirstlane(srcs[i + 2]);
        int s3 = __builtin_amdgcn_readfirstlane(srcs[i + 3]);
        float2 e0 = alE[s0 * NH1 + h];
        float2 e1 = alE[s1 * NH1 + h];
        float2 e2 = alE[s2 * NH1 + h];
        float2 e3 = alE[s3 * NH1 + h];
        float hv0 = __uint_as_float((unsigned int)h1b[s0 * HC + lane] << 16);
        float hv1 = __uint_as_float((unsigned int)h1b[s1 * HC + lane] << 16);
        float hv2 = __uint_as_float((unsigned int)h1b[s2 * HC + lane] << 16);
        float hv3 = __uint_as_float((unsigned int)h1b[s3 * HC + lane] << 16);
        float p0 = fmaxf(e0.x * E1d, e0.y * E2d);
        float p1 = fmaxf(e1.x * E1d, e1.y * E2d);
        float p2 = fmaxf(e2.x * E1d, e2.y * E2d);
        float p3 = fmaxf(e3.x * E1d, e3.y * E2d);
        den  += p0;  acc  = fmaf(p0, hv0, acc);
        denB += p1;  accB = fmaf(p1, hv1, accB);
        den  += p2;  acc  = fmaf(p2, hv2, acc);
        denB += p3;  accB = fmaf(p3, hv3, accB);
    }
    for (; i < end; ++i) {
        int s0 = __builtin_amdgcn_readfirstlane(srcs[i]);
        float2 e0 = alE[s0 * NH1 + h];
        float hv0 = __uint_as_float((unsigned int)h1b[s0 * HC + lane] << 16);
        float p0 = fmaxf(e0.x * E1d, e0.y * E2d);
        den += p0; acc = fmaf(p0, hv0, acc);
    }
    den += denB; acc += accB;

    float o = acc / den + b1[lane];
    o = (o > 0.f) ? o : expm1f(o);          // ELU
    // layer-2 linear: h2[node][oc] = sum_lane o * W2[lane][oc]
    float p0 = o * W2[lane * OUTC + 0];
    float p1 = o * W2[lane * OUTC + 1];
    for (int off = 1; off < 64; off <<= 1) {
        p0 += __shfl_xor(p0, off, 64);
        p1 += __shfl_xor(p1, off, 64);
    }
    if (lane == 0) {
        float l2s = p0 * a2s[0] + p1 * a2s[1];
        float l2d = p0 * a2d[0] + p1 * a2d[1];
        nd2[node] = make_float4(exp2f(l2s * L2E), exp2f(l2s * (NEGSL * L2E)),
                                p0, p1);
        al2d[node] = l2d;
    }
}

// ---------------- layer 2 aggregation (wave per node, lane per edge) ----------------

__global__ __launch_bounds__(256) void agg2(const float4* __restrict__ nd2,
                                            const float* __restrict__ al2d,
                                            const float* __restrict__ b2,
                                            const int* __restrict__ rowoff,
                                            const int* __restrict__ srcs,
                                            float* __restrict__ out) {
    int w = threadIdx.x >> 6, lane = threadIdx.x & 63;
    int n = blockIdx.x * 4 + w;
    if (n >= NNODES) return;
    float ald = al2d[n];
    float E1d = exp2f(ald * L2E);
    float E2d = exp2f(ald * (NEGSL * L2E));
    int beg = rowoff[n], end = rowoff[n + 1];
    float den = 0.f, a0 = 0.f, a1 = 0.f;
    for (int idx = beg + lane; idx < end; idx += 64) {
        int s = srcs[idx];
        float4 nd = nd2[s];
        float p = fmaxf(nd.x * E1d, nd.y * E2d);
        den += p;
        a0 = fmaf(p, nd.z, a0);
        a1 = fmaf(p, nd.w, a1);
    }
    for (int off = 1; off < 64; off <<= 1) {
        den += __shfl_xor(den, off, 64);
        a0  += __shfl_xor(a0, off, 64);
        a1  += __shfl_xor(a1, off, 64);
    }
    if (lane == 0) {
        out[n * 2 + 0] = a0 / den + b2[0];
        out[n * 2 + 1] = a1 / den + b2[1];
    }
}

// ---------------- launch ----------------

extern "C" void kernel_launch(void* const* d_in, const int* in_sizes, int n_in,
                              void* d_out, int out_size, void* d_ws, size_t ws_size,
                              hipStream_t stream) {
    const float* x   = (const float*)d_in[0];
    const int*   ei  = (const int*)  d_in[1];
    // d_in[2] = edge_attr (unused by reference)
    const float* W1  = (const float*)d_in[3];
    const float* a1s = (const float*)d_in[4];
    const float* a1d = (const float*)d_in[5];
    const float* b1  = (const float*)d_in[6];
    const float* W2  = (const float*)d_in[7];
    const float* a2s = (const float*)d_in[8];
    const float* a2d = (const float*)d_in[9];
    const float* b2  = (const float*)d_in[10];
    float* out = (float*)d_out;

    // workspace layout. CSR scratch (ebuf/carr/bsums) aliases the h1b+alE
    // region — both are dead until gemm1, which runs after buildD.
    char* ws = (char*)d_ws;
    unsigned short* h1b = (unsigned short*)ws;               // N*64 bf16 (12.8MB)
    float2* alE   = (float2*)(ws + (size_t)NNODES * HC * 2); // N*8 float2 (6.4MB)
    float* al1d_  = (float*)(alE + (size_t)NNODES * NH1);    // N*8 (3.2MB)
    float4* nd2   = (float4*)(al1d_ + (size_t)NNODES * NH1); // N float4 (1.6MB)
    float* al2d_  = (float*)(nd2 + NNODES);                  // N
    int* rowoff   = (int*)(al2d_ + NNODES);                  // N+1
    int* srcs     = rowoff + NNODES + 1;                     // E+N (13.2MB)
    // CSR scratch aliases h1b..alE (19.2MB >= 15.3MB needed)
    int* ebuf     = (int*)ws;                                // NEDGES (12.8MB)
    int* carr     = ebuf + NEDGES;                           // TOTC (2.45MB)
    int* bsums    = carr + TOTC;                             // ~2388 ints

    const int NB_SC  = (TOTC + 255) / 256;            // 2388
    const int NB_N4  = (NNODES + 3) / 4;              // 25000
    const int NB_G   = NNODES / 16;                   // 6250 (exact)

    // CSR build (LDS counting sort; no global atomics)
    histA<<<NBLK, 256, 0, stream>>>(ei, carr);
    scanA<<<NB_SC, 256, 0, stream>>>(carr, bsums);
    scanB<<<1, 1024, 0, stream>>>(bsums, NB_SC);
    scanC<<<NB_SC, 256, 0, stream>>>(carr, bsums);
    scatC<<<NBLK, 256, 0, stream>>>(ei, carr, ebuf);
    buildD<<<NBUCK, 256, 0, stream>>>(carr, ebuf, rowoff, srcs);

    // layer 1 linear + logit exponentials
    gemm1<<<NB_G, 256, 0, stream>>>(x, W1, a1s, a1d, h1b, alE, al1d_);

    // layer 1 aggregation + finalize + layer-2 linear/logits
    agg1<<<NB_N4, 256, 0, stream>>>(h1b, alE, al1d_, b1, W2, a2s, a2d,
                                    rowoff, srcs, nd2, al2d_);

    // layer 2 aggregation -> output
    agg2<<<NB_N4, 256, 0, stream>>>(nd2, al2d_, b2, rowoff, srcs, out);
}

// Round 10
// 279.566 us; speedup vs baseline: 1.8996x; 1.0096x over previous
//
#include <hip/hip_runtime.h>
#include <math.h>

#define NNODES 100000
#define NEDGES 3200000
#define ETOT   (NEDGES + NNODES)
#define IN_DIM 128
#define NH1    8
#define NC1    8
#define HC     64
#define OUTC   2
#define NEGSL  0.2f
#define L2E    1.44269504f

// counting-sort CSR build parameters
#define NBUCK 391                 // ceil(NNODES/256) coarse buckets (dst>>8)
#define EPB   2048                // edges per block in hist/scatter
#define NBLK  1563                // ceil(NEDGES/EPB)
#define TOTC  (NBUCK * NBLK)      // 611133 (bucket-major counts array)

// ---------------- CSR build (two-level LDS counting sort) ----------------

// per-block LDS histogram over coarse buckets -> counts[bucket][block]
__global__ __launch_bounds__(256) void histA(const int* __restrict__ ei,
                                             int* __restrict__ carr) {
    __shared__ int lh[NBUCK];
    int tid = threadIdx.x;
    for (int i = tid; i < NBUCK; i += 256) lh[i] = 0;
    __syncthreads();
    const int* dptr = ei + NEDGES;
    int base = blockIdx.x * EPB;
#pragma unroll
    for (int i = 0; i < EPB / 1024; i++) {
        int idx = base + i * 1024 + tid * 4;
        if (idx < NEDGES) {
            int4 d4 = *(const int4*)&dptr[idx];
            atomicAdd(&lh[d4.x >> 8], 1);
            atomicAdd(&lh[d4.y >> 8], 1);
            atomicAdd(&lh[d4.z >> 8], 1);
            atomicAdd(&lh[d4.w >> 8], 1);
        }
    }
    __syncthreads();
    for (int i = tid; i < NBUCK; i += 256)
        carr[i * NBLK + blockIdx.x] = lh[i];
}

// exclusive scan over TOTC counts (block-local) + block sums
__global__ __launch_bounds__(256) void scanA(int* __restrict__ carr,
                                             int* __restrict__ bsums) {
    int gid = blockIdx.x * 256 + threadIdx.x;
    int v = (gid < TOTC) ? carr[gid] : 0;
    int lane = threadIdx.x & 63, w = threadIdx.x >> 6;
    int x = v;
    for (int off = 1; off < 64; off <<= 1) {
        int y = __shfl_up(x, off, 64);
        if (lane >= off) x += y;
    }
    __shared__ int wt[4];
    if (lane == 63) wt[w] = x;
    __syncthreads();
    int add = 0;
    for (int i = 0; i < w; i++) add += wt[i];
    int incl = x + add;
    if (gid < TOTC) carr[gid] = incl - v;
    if (threadIdx.x == 255) bsums[blockIdx.x] = incl;
}

// scan of block sums; 4 elements per thread (supports nb <= 4096)
__global__ __launch_bounds__(1024) void scanB(int* __restrict__ bsums, int nb) {
    int tid = threadIdx.x;
    int base = tid * 4;
    int v[4]; int tot = 0;
#pragma unroll
    for (int j = 0; j < 4; j++) {
        v[j] = (base + j < nb) ? bsums[base + j] : 0;
        tot += v[j];
    }
    int lane = tid & 63, w = tid >> 6;
    int x = tot;
    for (int off = 1; off < 64; off <<= 1) {
        int y = __shfl_up(x, off, 64);
        if (lane >= off) x += y;
    }
    __shared__ int wt[16];
    if (lane == 63) wt[w] = x;
    __syncthreads();
    int add = 0;
    for (int i = 0; i < w; i++) add += wt[i];
    int pre = x + add - tot;   // exclusive prefix of this thread's chunk
#pragma unroll
    for (int j = 0; j < 4; j++) {
        if (base + j < nb) bsums[base + j] = pre;
        pre += v[j];
    }
}

__global__ __launch_bounds__(256) void scanC(int* __restrict__ carr,
                                             const int* __restrict__ bsums) {
    int gid = blockIdx.x * 256 + threadIdx.x;
    if (gid < TOTC) carr[gid] += bsums[gid >> 8];
}

// scatter edges into bucket-contiguous regions; rank via LDS atomic (any
// order within (block,bucket) is valid). Pack src (17b) | dst_low8 (<<17).
__global__ __launch_bounds__(256) void scatC(const int* __restrict__ ei,
                                             const int* __restrict__ soff,
                                             int* __restrict__ ebuf) {
    __shared__ int soffL[NBUCK];
    __shared__ int lh[NBUCK];
    int tid = threadIdx.x;
    for (int i = tid; i < NBUCK; i += 256) {
        soffL[i] = soff[i * NBLK + blockIdx.x];
        lh[i] = 0;
    }
    __syncthreads();
    int base = blockIdx.x * EPB;
#pragma unroll
    for (int i = 0; i < EPB / 1024; i++) {
        int idx = base + i * 1024 + tid * 4;
        if (idx < NEDGES) {
            int4 s4 = *(const int4*)&ei[idx];
            int4 d4 = *(const int4*)&ei[NEDGES + idx];
            int b0 = d4.x >> 8, b1 = d4.y >> 8, b2 = d4.z >> 8, b3 = d4.w >> 8;
            int r0 = atomicAdd(&lh[b0], 1);
            int r1 = atomicAdd(&lh[b1], 1);
            int r2 = atomicAdd(&lh[b2], 1);
            int r3 = atomicAdd(&lh[b3], 1);
            ebuf[soffL[b0] + r0] = s4.x | ((d4.x & 255) << 17);
            ebuf[soffL[b1] + r1] = s4.y | ((d4.y & 255) << 17);
            ebuf[soffL[b2] + r2] = s4.z | ((d4.z & 255) << 17);
            ebuf[soffL[b3] + r3] = s4.w | ((d4.w & 255) << 17);
        }
    }
}

// one block per bucket: fine count (256 nodes), LDS scan (+1 self-loop per
// node), emit rowoff + self-loops + final srcs.
__global__ __launch_bounds__(256) void buildD(const int* __restrict__ soff,
                                              const int* __restrict__ ebuf,
                                              int* __restrict__ rowoff,
                                              int* __restrict__ srcs) {
    int b = blockIdx.x, tid = threadIdx.x;
    int nb = min(256, NNODES - b * 256);
    int ebeg = soff[b * NBLK];
    int eend = (b == NBUCK - 1) ? NEDGES : soff[(b + 1) * NBLK];
    __shared__ int cnt2[256];
    __shared__ int rowL[256];
    __shared__ int wsum[4];
    cnt2[tid] = 0;
    __syncthreads();
    for (int e = ebeg + tid; e < eend; e += 256)
        atomicAdd(&cnt2[(ebuf[e] >> 17) & 255], 1);
    __syncthreads();
    // exclusive scan of (cnt2 + 1)
    int v = (tid < nb) ? cnt2[tid] + 1 : 0;
    int lane = tid & 63, w = tid >> 6;
    int x = v;
    for (int off = 1; off < 64; off <<= 1) {
        int y = __shfl_up(x, off, 64);
        if (lane >= off) x += y;
    }
    if (lane == 63) wsum[w] = x;
    __syncthreads();
    int add = 0;
    for (int i = 0; i < w; i++) add += wsum[i];
    int fbase = ebeg + b * 256;              // + self-loops of earlier buckets
    int row = fbase + x + add - v;           // exclusive
    if (tid < nb) {
        rowL[tid] = row;
        int gnode = b * 256 + tid;
        rowoff[gnode] = row;
        srcs[row + cnt2[tid]] = gnode;       // self-loop in last slot of row
        if (gnode == NNODES - 1) rowoff[NNODES] = ETOT;
    }
    __syncthreads();
    cnt2[tid] = 0;                           // reuse as rank counters
    __syncthreads();
    for (int e = ebeg + tid; e < eend; e += 256) {
        int wv = ebuf[e];
        int dl = (wv >> 17) & 255;
        int r = atomicAdd(&cnt2[dl], 1);
        srcs[rowL[dl] + r] = wv & 0x1FFFF;
    }
}

// ---------------- layer 1 linear + attention logit exponentials ----------------
// h1 stored as bf16 (RNE) — halves the agg1 gather traffic.
// alE[node*8+h] = (exp(al_src), exp(0.2*al_src)); al1d kept raw.

__global__ __launch_bounds__(256) void gemm1(const float* __restrict__ x,
                                             const float* __restrict__ W1,
                                             const float* __restrict__ a1s,
                                             const float* __restrict__ a1d,
                                             unsigned short* __restrict__ h1b,
                                             float2* __restrict__ alE,
                                             float* __restrict__ al1d) {
    __shared__ float sW[IN_DIM * HC];   // 32 KB
    int tid = threadIdx.x;
    const float4* W4 = (const float4*)W1;
    float4* sW4 = (float4*)sW;
#pragma unroll
    for (int i = 0; i < 8; i++)          // 2048 float4 / 256 threads
        sW4[tid + i * 256] = W4[tid + i * 256];
    __syncthreads();

    int w = __builtin_amdgcn_readfirstlane(tid >> 6);
    int lane = tid & 63;
    int node0 = blockIdx.x * 16 + w * 4;       // 6250 blocks * 16 = 100000 exact
    const float* xr = x + (size_t)node0 * IN_DIM;

    float acc0 = 0.f, acc1 = 0.f, acc2 = 0.f, acc3 = 0.f;
#pragma unroll 8
    for (int k = 0; k < IN_DIM; k++) {
        float wv = sW[k * HC + lane];
        acc0 = fmaf(xr[k], wv, acc0);
        acc1 = fmaf(xr[IN_DIM + k], wv, acc1);
        acc2 = fmaf(xr[2 * IN_DIM + k], wv, acc2);
        acc3 = fmaf(xr[3 * IN_DIM + k], wv, acc3);
    }

    float accs[4] = {acc0, acc1, acc2, acc3};
    int head = lane >> 3, c = lane & 7;
    float as = a1s[head * NC1 + c], adv = a1d[head * NC1 + c];
#pragma unroll
    for (int n = 0; n < 4; n++) {
        int node = node0 + n;
        unsigned int u = __float_as_uint(accs[n]);
        h1b[node * HC + lane] =
            (unsigned short)((u + 0x7FFF + ((u >> 16) & 1)) >> 16);  // RNE bf16
        float ps = accs[n] * as;
        float pd = accs[n] * adv;
        for (int off = 1; off < 8; off <<= 1) {
            ps += __shfl_xor(ps, off, 64);
            pd += __shfl_xor(pd, off, 64);
        }
        if (c == 0) {
            alE[node * NH1 + head] = make_float2(exp2f(ps * L2E),
                                                 exp2f(ps * (NEGSL * L2E)));
            al1d[node * NH1 + head] = pd;
        }
    }
}

// ---------------- layer 1 aggregation ----------------
// wave per node; 8-edge software pipeline: read 8 srcs (scalarized), issue
// all 16 gathers (alE + h1b), then do the math — ~16 outstanding L2-misses
// per wave to cover the L3 service latency. exp(LeakyReLU) == max of two
// precomputed exponential products; softmax shift cancels in acc/den.

__global__ __launch_bounds__(256) void agg1(const unsigned short* __restrict__ h1b,
                                            const float2* __restrict__ alE,
                                            const float* __restrict__ al1d,
                                            const float* __restrict__ b1,
                                            const float* __restrict__ W2,
                                            const float* __restrict__ a2s,
                                            const float* __restrict__ a2d,
                                            const int* __restrict__ rowoff,
                                            const int* __restrict__ srcs,
                                            float4* __restrict__ nd2,
                                            float* __restrict__ al2d) {
    int w = threadIdx.x >> 6, lane = threadIdx.x & 63;
    int node = blockIdx.x * 4 + w;
    if (node >= NNODES) return;
    int h = lane >> 3;
    float ald = al1d[node * NH1 + h];
    float E1d = exp2f(ald * L2E);
    float E2d = exp2f(ald * (NEGSL * L2E));
    int beg = __builtin_amdgcn_readfirstlane(rowoff[node]);
    int end = __builtin_amdgcn_readfirstlane(rowoff[node + 1]);

    float den = 0.f, acc = 0.f, denB = 0.f, accB = 0.f;
    int i = beg;
    for (; i + 8 <= end; i += 8) {
        int s[8];
#pragma unroll
        for (int j = 0; j < 8; j++)
            s[j] = __builtin_amdgcn_readfirstlane(srcs[i + j]);
        float2 e[8];
#pragma unroll
        for (int j = 0; j < 8; j++) e[j] = alE[s[j] * NH1 + h];
        float hv[8];
#pragma unroll
        for (int j = 0; j < 8; j++)
            hv[j] = __uint_as_float((unsigned int)h1b[s[j] * HC + lane] << 16);
#pragma unroll
        for (int j = 0; j < 8; j += 2) {
            float p0 = fmaxf(e[j].x * E1d, e[j].y * E2d);
            float p1 = fmaxf(e[j + 1].x * E1d, e[j + 1].y * E2d);
            den  += p0;  acc  = fmaf(p0, hv[j], acc);
            denB += p1;  accB = fmaf(p1, hv[j + 1], accB);
        }
    }
    for (; i + 4 <= end; i += 4) {
        int s[4];
#pragma unroll
        for (int j = 0; j < 4; j++)
            s[j] = __builtin_amdgcn_readfirstlane(srcs[i + j]);
        float2 e[4];
#pragma unroll
        for (int j = 0; j < 4; j++) e[j] = alE[s[j] * NH1 + h];
        float hv[4];
#pragma unroll
        for (int j = 0; j < 4; j++)
            hv[j] = __uint_as_float((unsigned int)h1b[s[j] * HC + lane] << 16);
#pragma unroll
        for (int j = 0; j < 4; j += 2) {
            float p0 = fmaxf(e[j].x * E1d, e[j].y * E2d);
            float p1 = fmaxf(e[j + 1].x * E1d, e[j + 1].y * E2d);
            den  += p0;  acc  = fmaf(p0, hv[j], acc);
            denB += p1;  accB = fmaf(p1, hv[j + 1], accB);
        }
    }
    for (; i < end; ++i) {
        int s0 = __builtin_amdgcn_readfirstlane(srcs[i]);
        float2 e0 = alE[s0 * NH1 + h];
        float hv0 = __uint_as_float((unsigned int)h1b[s0 * HC + lane] << 16);
        float p0 = fmaxf(e0.x * E1d, e0.y * E2d);
        den += p0; acc = fmaf(p0, hv0, acc);
    }
    den += denB; acc += accB;

    float o = acc / den + b1[lane];
    o = (o > 0.f) ? o : expm1f(o);          // ELU
    // layer-2 linear: h2[node][oc] = sum_lane o * W2[lane][oc]
    float p0 = o * W2[lane * OUTC + 0];
    float p1 = o * W2[lane * OUTC + 1];
    for (int off = 1; off < 64; off <<= 1) {
        p0 += __shfl_xor(p0, off, 64);
        p1 += __shfl_xor(p1, off, 64);
    }
    if (lane == 0) {
        float l2s = p0 * a2s[0] + p1 * a2s[1];
        float l2d = p0 * a2d[0] + p1 * a2d[1];
        nd2[node] = make_float4(exp2f(l2s * L2E), exp2f(l2s * (NEGSL * L2E)),
                                p0, p1);
        al2d[node] = l2d;
    }
}

// ---------------- layer 2 aggregation (wave per node, lane per edge) ----------------

__global__ __launch_bounds__(256) void agg2(const float4* __restrict__ nd2,
                                            const float* __restrict__ al2d,
                                            const float* __restrict__ b2,
                                            const int* __restrict__ rowoff,
                                            const int* __restrict__ srcs,
                                            float* __restrict__ out) {
    int w = threadIdx.x >> 6, lane = threadIdx.x & 63;
    int n = blockIdx.x * 4 + w;
    if (n >= NNODES) return;
    float ald = al2d[n];
    float E1d = exp2f(ald * L2E);
    float E2d = exp2f(ald * (NEGSL * L2E));
    int beg = rowoff[n], end = rowoff[n + 1];
    float den = 0.f, a0 = 0.f, a1 = 0.f;
    for (int idx = beg + lane; idx < end; idx += 64) {
        int s = srcs[idx];
        float4 nd = nd2[s];
        float p = fmaxf(nd.x * E1d, nd.y * E2d);
        den += p;
        a0 = fmaf(p, nd.z, a0);
        a1 = fmaf(p, nd.w, a1);
    }
    for (int off = 1; off < 64; off <<= 1) {
        den += __shfl_xor(den, off, 64);
        a0  += __shfl_xor(a0, off, 64);
        a1  += __shfl_xor(a1, off, 64);
    }
    if (lane == 0) {
        out[n * 2 + 0] = a0 / den + b2[0];
        out[n * 2 + 1] = a1 / den + b2[1];
    }
}

// ---------------- launch ----------------

extern "C" void kernel_launch(void* const* d_in, const int* in_sizes, int n_in,
                              void* d_out, int out_size, void* d_ws, size_t ws_size,
                              hipStream_t stream) {
    const float* x   = (const float*)d_in[0];
    const int*   ei  = (const int*)  d_in[1];
    // d_in[2] = edge_attr (unused by reference)
    const float* W1  = (const float*)d_in[3];
    const float* a1s = (const float*)d_in[4];
    const float* a1d = (const float*)d_in[5];
    const float* b1  = (const float*)d_in[6];
    const float* W2  = (const float*)d_in[7];
    const float* a2s = (const float*)d_in[8];
    const float* a2d = (const float*)d_in[9];
    const float* b2  = (const float*)d_in[10];
    float* out = (float*)d_out;

    // workspace layout. CSR scratch (ebuf/carr/bsums) aliases the h1b+alE
    // region — both are dead until gemm1, which runs after buildD.
    char* ws = (char*)d_ws;
    unsigned short* h1b = (unsigned short*)ws;               // N*64 bf16 (12.8MB)
    float2* alE   = (float2*)(ws + (size_t)NNODES * HC * 2); // N*8 float2 (6.4MB)
    float* al1d_  = (float*)(alE + (size_t)NNODES * NH1);    // N*8 (3.2MB)
    float4* nd2   = (float4*)(al1d_ + (size_t)NNODES * NH1); // N float4 (1.6MB)
    float* al2d_  = (float*)(nd2 + NNODES);                  // N
    int* rowoff   = (int*)(al2d_ + NNODES);                  // N+1
    int* srcs     = rowoff + NNODES + 1;                     // E+N (13.2MB)
    // CSR scratch aliases h1b..alE (19.2MB >= 15.3MB needed)
    int* ebuf     = (int*)ws;                                // NEDGES (12.8MB)
    int* carr     = ebuf + NEDGES;                           // TOTC (2.45MB)
    int* bsums    = carr + TOTC;                             // ~2388 ints

    const int NB_SC  = (TOTC + 255) / 256;            // 2388
    const int NB_N4  = (NNODES + 3) / 4;              // 25000
    const int NB_G   = NNODES / 16;                   // 6250 (exact)

    // CSR build (LDS counting sort; no global atomics)
    histA<<<NBLK, 256, 0, stream>>>(ei, carr);
    scanA<<<NB_SC, 256, 0, stream>>>(carr, bsums);
    scanB<<<1, 1024, 0, stream>>>(bsums, NB_SC);
    scanC<<<NB_SC, 256, 0, stream>>>(carr, bsums);
    scatC<<<NBLK, 256, 0, stream>>>(ei, carr, ebuf);
    buildD<<<NBUCK, 256, 0, stream>>>(carr, ebuf, rowoff, srcs);

    // layer 1 linear + logit exponentials
    gemm1<<<NB_G, 256, 0, stream>>>(x, W1, a1s, a1d, h1b, alE, al1d_);

    // layer 1 aggregation + finalize + layer-2 linear/logits
    agg1<<<NB_N4, 256, 0, stream>>>(h1b, alE, al1d_, b1, W2, a2s, a2d,
                                    rowoff, srcs, nd2, al2d_);

    // layer 2 aggregation -> output
    agg2<<<NB_N4, 256, 0, stream>>>(nd2, al2d_, b2, rowoff, srcs, out);
}

// Round 11
// 268.409 us; speedup vs baseline: 1.9785x; 1.0416x over previous
//
#include <hip/hip_runtime.h>
#include <math.h>

#define NNODES 100000
#define NEDGES 3200000
#define ETOT   (NEDGES + NNODES)
#define IN_DIM 128
#define NH1    8
#define NC1    8
#define HC     64
#define OUTC   2
#define NEGSL  0.2f
#define L2E    1.44269504f

// counting-sort CSR build parameters
#define NBUCK 391                 // ceil(NNODES/256) coarse buckets (dst>>8)
#define EPB   4096                // edges per block in hist/scatter
#define NBLK  782                 // ceil(NEDGES/EPB)
#define TOTC  (NBUCK * NBLK)      // 305762 (bucket-major counts array)

// ---------------- CSR build (two-level LDS counting sort) ----------------

// per-block LDS histogram over coarse buckets -> counts[bucket][block]
__global__ __launch_bounds__(256) void histA(const int* __restrict__ ei,
                                             int* __restrict__ carr) {
    __shared__ int lh[NBUCK];
    int tid = threadIdx.x;
    for (int i = tid; i < NBUCK; i += 256) lh[i] = 0;
    __syncthreads();
    const int* dptr = ei + NEDGES;
    int base = blockIdx.x * EPB;
#pragma unroll
    for (int i = 0; i < EPB / 1024; i++) {
        int idx = base + i * 1024 + tid * 4;
        if (idx < NEDGES) {
            int4 d4 = *(const int4*)&dptr[idx];
            atomicAdd(&lh[d4.x >> 8], 1);
            atomicAdd(&lh[d4.y >> 8], 1);
            atomicAdd(&lh[d4.z >> 8], 1);
            atomicAdd(&lh[d4.w >> 8], 1);
        }
    }
    __syncthreads();
    for (int i = tid; i < NBUCK; i += 256)
        carr[i * NBLK + blockIdx.x] = lh[i];
}

// exclusive scan over TOTC counts (block-local) + block sums
__global__ __launch_bounds__(256) void scanA(int* __restrict__ carr,
                                             int* __restrict__ bsums) {
    int gid = blockIdx.x * 256 + threadIdx.x;
    int v = (gid < TOTC) ? carr[gid] : 0;
    int lane = threadIdx.x & 63, w = threadIdx.x >> 6;
    int x = v;
    for (int off = 1; off < 64; off <<= 1) {
        int y = __shfl_up(x, off, 64);
        if (lane >= off) x += y;
    }
    __shared__ int wt[4];
    if (lane == 63) wt[w] = x;
    __syncthreads();
    int add = 0;
    for (int i = 0; i < w; i++) add += wt[i];
    int incl = x + add;
    if (gid < TOTC) carr[gid] = incl - v;
    if (threadIdx.x == 255) bsums[blockIdx.x] = incl;
}

// scan of block sums; 4 elements per thread (supports nb <= 4096)
__global__ __launch_bounds__(1024) void scanB(int* __restrict__ bsums, int nb) {
    int tid = threadIdx.x;
    int base = tid * 4;
    int v[4]; int tot = 0;
#pragma unroll
    for (int j = 0; j < 4; j++) {
        v[j] = (base + j < nb) ? bsums[base + j] : 0;
        tot += v[j];
    }
    int lane = tid & 63, w = tid >> 6;
    int x = tot;
    for (int off = 1; off < 64; off <<= 1) {
        int y = __shfl_up(x, off, 64);
        if (lane >= off) x += y;
    }
    __shared__ int wt[16];
    if (lane == 63) wt[w] = x;
    __syncthreads();
    int add = 0;
    for (int i = 0; i < w; i++) add += wt[i];
    int pre = x + add - tot;   // exclusive prefix of this thread's chunk
#pragma unroll
    for (int j = 0; j < 4; j++) {
        if (base + j < nb) bsums[base + j] = pre;
        pre += v[j];
    }
}

__global__ __launch_bounds__(256) void scanC(int* __restrict__ carr,
                                             const int* __restrict__ bsums) {
    int gid = blockIdx.x * 256 + threadIdx.x;
    if (gid < TOTC) carr[gid] += bsums[gid >> 8];
}

// scatter edges into bucket-contiguous regions; rank via LDS atomic (any
// order within (block,bucket) is valid). Pack src (17b) | dst_low8 (<<17).
__global__ __launch_bounds__(256) void scatC(const int* __restrict__ ei,
                                             const int* __restrict__ soff,
                                             int* __restrict__ ebuf) {
    __shared__ int soffL[NBUCK];
    __shared__ int lh[NBUCK];
    int tid = threadIdx.x;
    for (int i = tid; i < NBUCK; i += 256) {
        soffL[i] = soff[i * NBLK + blockIdx.x];
        lh[i] = 0;
    }
    __syncthreads();
    int base = blockIdx.x * EPB;
#pragma unroll
    for (int i = 0; i < EPB / 1024; i++) {
        int idx = base + i * 1024 + tid * 4;
        if (idx < NEDGES) {
            int4 s4 = *(const int4*)&ei[idx];
            int4 d4 = *(const int4*)&ei[NEDGES + idx];
            int b0 = d4.x >> 8, b1 = d4.y >> 8, b2 = d4.z >> 8, b3 = d4.w >> 8;
            int r0 = atomicAdd(&lh[b0], 1);
            int r1 = atomicAdd(&lh[b1], 1);
            int r2 = atomicAdd(&lh[b2], 1);
            int r3 = atomicAdd(&lh[b3], 1);
            ebuf[soffL[b0] + r0] = s4.x | ((d4.x & 255) << 17);
            ebuf[soffL[b1] + r1] = s4.y | ((d4.y & 255) << 17);
            ebuf[soffL[b2] + r2] = s4.z | ((d4.z & 255) << 17);
            ebuf[soffL[b3] + r3] = s4.w | ((d4.w & 255) << 17);
        }
    }
}

// one block per bucket: fine count (256 nodes), LDS scan (+1 self-loop per
// node), emit rowoff + self-loops + final srcs.
__global__ __launch_bounds__(256) void buildD(const int* __restrict__ soff,
                                              const int* __restrict__ ebuf,
                                              int* __restrict__ rowoff,
                                              int* __restrict__ srcs) {
    int b = blockIdx.x, tid = threadIdx.x;
    int nb = min(256, NNODES - b * 256);
    int ebeg = soff[b * NBLK];
    int eend = (b == NBUCK - 1) ? NEDGES : soff[(b + 1) * NBLK];
    __shared__ int cnt2[256];
    __shared__ int rowL[256];
    __shared__ int wsum[4];
    cnt2[tid] = 0;
    __syncthreads();
    for (int e = ebeg + tid; e < eend; e += 256)
        atomicAdd(&cnt2[(ebuf[e] >> 17) & 255], 1);
    __syncthreads();
    // exclusive scan of (cnt2 + 1)
    int v = (tid < nb) ? cnt2[tid] + 1 : 0;
    int lane = tid & 63, w = tid >> 6;
    int x = v;
    for (int off = 1; off < 64; off <<= 1) {
        int y = __shfl_up(x, off, 64);
        if (lane >= off) x += y;
    }
    if (lane == 63) wsum[w] = x;
    __syncthreads();
    int add = 0;
    for (int i = 0; i < w; i++) add += wsum[i];
    int fbase = ebeg + b * 256;              // + self-loops of earlier buckets
    int row = fbase + x + add - v;           // exclusive
    if (tid < nb) {
        rowL[tid] = row;
        int gnode = b * 256 + tid;
        rowoff[gnode] = row;
        srcs[row + cnt2[tid]] = gnode;       // self-loop in last slot of row
        if (gnode == NNODES - 1) rowoff[NNODES] = ETOT;
    }
    __syncthreads();
    cnt2[tid] = 0;                           // reuse as rank counters
    __syncthreads();
    for (int e = ebeg + tid; e < eend; e += 256) {
        int wv = ebuf[e];
        int dl = (wv >> 17) & 255;
        int r = atomicAdd(&cnt2[dl], 1);
        srcs[rowL[dl] + r] = wv & 0x1FFFF;
    }
}

// ---------------- layer 1 linear + attention logit exponentials ----------------
// h1 stored as bf16 (RNE) — halves the agg1 gather traffic.
// alE[node*8+h] = (exp(al_src), exp(0.2*al_src)); al1d kept raw.

__global__ __launch_bounds__(256) void gemm1(const float* __restrict__ x,
                                             const float* __restrict__ W1,
                                             const float* __restrict__ a1s,
                                             const float* __restrict__ a1d,
                                             unsigned short* __restrict__ h1b,
                                             float2* __restrict__ alE,
                                             float* __restrict__ al1d) {
    __shared__ float sW[IN_DIM * HC];   // 32 KB
    int tid = threadIdx.x;
    const float4* W4 = (const float4*)W1;
    float4* sW4 = (float4*)sW;
#pragma unroll
    for (int i = 0; i < 8; i++)          // 2048 float4 / 256 threads
        sW4[tid + i * 256] = W4[tid + i * 256];
    __syncthreads();

    int w = __builtin_amdgcn_readfirstlane(tid >> 6);
    int lane = tid & 63;
    int node0 = blockIdx.x * 16 + w * 4;       // 6250 blocks * 16 = 100000 exact
    const float* xr = x + (size_t)node0 * IN_DIM;

    float acc0 = 0.f, acc1 = 0.f, acc2 = 0.f, acc3 = 0.f;
#pragma unroll 8
    for (int k = 0; k < IN_DIM; k++) {
        float wv = sW[k * HC + lane];
        acc0 = fmaf(xr[k], wv, acc0);
        acc1 = fmaf(xr[IN_DIM + k], wv, acc1);
        acc2 = fmaf(xr[2 * IN_DIM + k], wv, acc2);
        acc3 = fmaf(xr[3 * IN_DIM + k], wv, acc3);
    }

    float accs[4] = {acc0, acc1, acc2, acc3};
    int head = lane >> 3, c = lane & 7;
    float as = a1s[head * NC1 + c], adv = a1d[head * NC1 + c];
#pragma unroll
    for (int n = 0; n < 4; n++) {
        int node = node0 + n;
        unsigned int u = __float_as_uint(accs[n]);
        h1b[node * HC + lane] =
            (unsigned short)((u + 0x7FFF + ((u >> 16) & 1)) >> 16);  // RNE bf16
        float ps = accs[n] * as;
        float pd = accs[n] * adv;
        for (int off = 1; off < 8; off <<= 1) {
            ps += __shfl_xor(ps, off, 64);
            pd += __shfl_xor(pd, off, 64);
        }
        if (c == 0) {
            alE[node * NH1 + head] = make_float2(exp2f(ps * L2E),
                                                 exp2f(ps * (NEGSL * L2E)));
            al1d[node * NH1 + head] = pd;
        }
    }
}

// ---------------- layer 1 aggregation ----------------
// wave per node; TWO edges per wave-instruction: lane = ep*32 + c where
// ep = edge parity, c = channel pair (channels 2c,2c+1; head = c>>2).
// Per edge pair: 1 srcs dword, 1 alE float2, 1 h1b dword (2 bf16) — half
// the vmem instructions of one-edge-per-wave. den per lane is per-head
// (4 lanes of a head-group hold identical p; summed only across the two
// ep halves via shfl_xor(32)). exp(LeakyReLU)==max of precomputed exps.

__global__ __launch_bounds__(256) void agg1(const unsigned short* __restrict__ h1b,
                                            const float2* __restrict__ alE,
                                            const float* __restrict__ al1d,
                                            const float* __restrict__ b1,
                                            const float* __restrict__ W2,
                                            const float* __restrict__ a2s,
                                            const float* __restrict__ a2d,
                                            const int* __restrict__ rowoff,
                                            const int* __restrict__ srcs,
                                            float4* __restrict__ nd2,
                                            float* __restrict__ al2d) {
    int w = threadIdx.x >> 6, lane = threadIdx.x & 63;
    int node = blockIdx.x * 4 + w;
    if (node >= NNODES) return;
    int ep = lane >> 5;          // which edge of the pair
    int c  = lane & 31;          // channel pair id: channels 2c, 2c+1
    int hh = c >> 2;             // head of both channels
    float ald = al1d[node * NH1 + hh];
    float E1d = exp2f(ald * L2E);
    float E2d = exp2f(ald * (NEGSL * L2E));
    int beg = __builtin_amdgcn_readfirstlane(rowoff[node]);
    int end = __builtin_amdgcn_readfirstlane(rowoff[node + 1]);

    float den = 0.f, acc0 = 0.f, acc1 = 0.f;
    float denB = 0.f, acc0B = 0.f, acc1B = 0.f;
    int i = beg;
    for (; i + 4 <= end; i += 4) {
        int sa = srcs[i + ep];
        int sb = srcs[i + 2 + ep];
        float2 ea = alE[sa * NH1 + hh];
        float2 eb = alE[sb * NH1 + hh];
        unsigned int ha = *(const unsigned int*)&h1b[sa * HC + 2 * c];
        unsigned int hb = *(const unsigned int*)&h1b[sb * HC + 2 * c];
        float pa = fmaxf(ea.x * E1d, ea.y * E2d);
        float pb = fmaxf(eb.x * E1d, eb.y * E2d);
        float va0 = __uint_as_float(ha << 16);
        float va1 = __uint_as_float(ha & 0xFFFF0000u);
        float vb0 = __uint_as_float(hb << 16);
        float vb1 = __uint_as_float(hb & 0xFFFF0000u);
        den  += pa;  acc0  = fmaf(pa, va0, acc0);  acc1  = fmaf(pa, va1, acc1);
        denB += pb;  acc0B = fmaf(pb, vb0, acc0B); acc1B = fmaf(pb, vb1, acc1B);
    }
    for (; i < end; i += 2) {
        int ia = i + ep;
        bool valid = ia < end;
        int sa = srcs[valid ? ia : end - 1];
        float2 ea = alE[sa * NH1 + hh];
        unsigned int ha = *(const unsigned int*)&h1b[sa * HC + 2 * c];
        float pa = fmaxf(ea.x * E1d, ea.y * E2d);
        pa = valid ? pa : 0.f;
        float va0 = __uint_as_float(ha << 16);
        float va1 = __uint_as_float(ha & 0xFFFF0000u);
        den += pa; acc0 = fmaf(pa, va0, acc0); acc1 = fmaf(pa, va1, acc1);
    }
    den += denB; acc0 += acc0B; acc1 += acc1B;
    // combine the two edge-parity halves
    den  += __shfl_xor(den, 32, 64);
    acc0 += __shfl_xor(acc0, 32, 64);
    acc1 += __shfl_xor(acc1, 32, 64);

    float2 b1v = *(const float2*)&b1[2 * c];
    float o0 = acc0 / den + b1v.x;
    float o1 = acc1 / den + b1v.y;
    o0 = (o0 > 0.f) ? o0 : expm1f(o0);       // ELU
    o1 = (o1 > 0.f) ? o1 : expm1f(o1);
    // layer-2 linear: channels 2c,2c+1 against W2 rows (float4 = 2 rows)
    float4 w2v = *(const float4*)&W2[4 * c];
    float p0 = o0 * w2v.x + o1 * w2v.z;
    float p1 = o0 * w2v.y + o1 * w2v.w;
    for (int off = 1; off < 32; off <<= 1) {
        p0 += __shfl_xor(p0, off, 64);
        p1 += __shfl_xor(p1, off, 64);
    }
    if (lane == 0) {
        float l2s = p0 * a2s[0] + p1 * a2s[1];
        float l2d = p0 * a2d[0] + p1 * a2d[1];
        nd2[node] = make_float4(exp2f(l2s * L2E), exp2f(l2s * (NEGSL * L2E)),
                                p0, p1);
        al2d[node] = l2d;
    }
}

// ---------------- layer 2 aggregation (wave per node, lane per edge) ----------------

__global__ __launch_bounds__(256) void agg2(const float4* __restrict__ nd2,
                                            const float* __restrict__ al2d,
                                            const float* __restrict__ b2,
                                            const int* __restrict__ rowoff,
                                            const int* __restrict__ srcs,
                                            float* __restrict__ out) {
    int w = threadIdx.x >> 6, lane = threadIdx.x & 63;
    int n = blockIdx.x * 4 + w;
    if (n >= NNODES) return;
    float ald = al2d[n];
    float E1d = exp2f(ald * L2E);
    float E2d = exp2f(ald * (NEGSL * L2E));
    int beg = rowoff[n], end = rowoff[n + 1];
    float den = 0.f, a0 = 0.f, a1 = 0.f;
    for (int idx = beg + lane; idx < end; idx += 64) {
        int s = srcs[idx];
        float4 nd = nd2[s];
        float p = fmaxf(nd.x * E1d, nd.y * E2d);
        den += p;
        a0 = fmaf(p, nd.z, a0);
        a1 = fmaf(p, nd.w, a1);
    }
    for (int off = 1; off < 64; off <<= 1) {
        den += __shfl_xor(den, off, 64);
        a0  += __shfl_xor(a0, off, 64);
        a1  += __shfl_xor(a1, off, 64);
    }
    if (lane == 0) {
        out[n * 2 + 0] = a0 / den + b2[0];
        out[n * 2 + 1] = a1 / den + b2[1];
    }
}

// ---------------- launch ----------------

extern "C" void kernel_launch(void* const* d_in, const int* in_sizes, int n_in,
                              void* d_out, int out_size, void* d_ws, size_t ws_size,
                              hipStream_t stream) {
    const float* x   = (const float*)d_in[0];
    const int*   ei  = (const int*)  d_in[1];
    // d_in[2] = edge_attr (unused by reference)
    const float* W1  = (const float*)d_in[3];
    const float* a1s = (const float*)d_in[4];
    const float* a1d = (const float*)d_in[5];
    const float* b1  = (const float*)d_in[6];
    const float* W2  = (const float*)d_in[7];
    const float* a2s = (const float*)d_in[8];
    const float* a2d = (const float*)d_in[9];
    const float* b2  = (const float*)d_in[10];
    float* out = (float*)d_out;

    // workspace layout. CSR scratch (ebuf/carr/bsums) aliases the h1b+alE
    // region — both are dead until gemm1, which runs after buildD.
    char* ws = (char*)d_ws;
    unsigned short* h1b = (unsigned short*)ws;               // N*64 bf16 (12.8MB)
    float2* alE   = (float2*)(ws + (size_t)NNODES * HC * 2); // N*8 float2 (6.4MB)
    float* al1d_  = (float*)(alE + (size_t)NNODES * NH1);    // N*8 (3.2MB)
    float4* nd2   = (float4*)(al1d_ + (size_t)NNODES * NH1); // N float4 (1.6MB)
    float* al2d_  = (float*)(nd2 + NNODES);                  // N
    int* rowoff   = (int*)(al2d_ + NNODES);                  // N+1
    int* srcs     = rowoff + NNODES + 1;                     // E+N (13.2MB)
    // CSR scratch aliases h1b..alE (19.2MB >= 14.1MB needed)
    int* ebuf     = (int*)ws;                                // NEDGES (12.8MB)
    int* carr     = ebuf + NEDGES;                           // TOTC (1.22MB)
    int* bsums    = carr + TOTC;                             // ~1195 ints

    const int NB_SC  = (TOTC + 255) / 256;            // 1195
    const int NB_N4  = (NNODES + 3) / 4;              // 25000
    const int NB_G   = NNODES / 16;                   // 6250 (exact)

    // CSR build (LDS counting sort; no global atomics)
    histA<<<NBLK, 256, 0, stream>>>(ei, carr);
    scanA<<<NB_SC, 256, 0, stream>>>(carr, bsums);
    scanB<<<1, 1024, 0, stream>>>(bsums, NB_SC);
    scanC<<<NB_SC, 256, 0, stream>>>(carr, bsums);
    scatC<<<NBLK, 256, 0, stream>>>(ei, carr, ebuf);
    buildD<<<NBUCK, 256, 0, stream>>>(carr, ebuf, rowoff, srcs);

    // layer 1 linear + logit exponentials
    gemm1<<<NB_G, 256, 0, stream>>>(x, W1, a1s, a1d, h1b, alE, al1d_);

    // layer 1 aggregation + finalize + layer-2 linear/logits
    agg1<<<NB_N4, 256, 0, stream>>>(h1b, alE, al1d_, b1, W2, a2s, a2d,
                                    rowoff, srcs, nd2, al2d_);

    // layer 2 aggregation -> output
    agg2<<<NB_N4, 256, 0, stream>>>(nd2, al2d_, b2, rowoff, srcs, out);
}